// Round 15
// baseline (186.847 us; speedup 1.0000x reference)
//
#include <hip/hip_runtime.h>
#include <math.h>

#define N_NODES 2048
#define N_EDGES 4096
#define DIM 128
#define HEADS 4
#define DH 32
#define NCLS 16
#define TOPK 1024
#define NBR_CAP 64
#define NSPLIT 4
#define QB 32  // queries per attn_node unit
#define SCALE 0.17677669529663687f  // 1/sqrt(32)

#define FMA4(ACC, AS, BV)                                       \
  ACC.x = fmaf(AS, BV.x, ACC.x); ACC.y = fmaf(AS, BV.y, ACC.y); \
  ACC.z = fmaf(AS, BV.z, ACC.z); ACC.w = fmaf(AS, BV.w, ACC.w)

__device__ __forceinline__ float wave_reduce_sum(float v) {
#pragma unroll
  for (int o = 32; o > 0; o >>= 1) v += __shfl_xor(v, o, 64);
  return v;
}

// ============ K1: scores (0..1535) + nbr lists (1536..2559, 4 q/block) +
//              W_fused (2560..2563) + b_fused & counter-zero (2564) =========
__global__ __launch_bounds__(256) void prep_kernel(
    const float* __restrict__ nf, const float* __restrict__ ef,
    const float* __restrict__ w_rn, const float* __restrict__ b_rn,
    const float* __restrict__ w_re, const float* __restrict__ b_re,
    const int* __restrict__ src, const int* __restrict__ dst,
    const float* __restrict__ wo_n, const float* __restrict__ bo_n,
    const float* __restrict__ w_ne, const float* __restrict__ b_ne,
    float* __restrict__ ns, float* __restrict__ es, int* __restrict__ nbr,
    int* __restrict__ deg, float* __restrict__ wfu, float* __restrict__ bfu,
    int* __restrict__ acnt) {
  int tid = threadIdx.x;
  int bid = blockIdx.x;
  if (bid < 1536) {  // router scores: 4 rows/block, 1 per wave
    int wid = tid >> 6, lane = tid & 63;
    int row = bid * 4 + wid;
    const float* feat;
    const float* w;
    float b;
    float* scp;
    if (row < N_NODES) {
      feat = nf + (size_t)row * DIM;
      w = w_rn; b = b_rn[0];
      scp = ns + row;
    } else {
      int r = row - N_NODES;
      feat = ef + (size_t)r * DIM;
      w = w_re; b = b_re[0];
      scp = es + r;
    }
    float d = feat[lane] * w[lane] + feat[lane + 64] * w[lane + 64];
    d = wave_reduce_sum(d);
    if (lane == 0) *scp = 1.0f / (1.0f + __expf(-(d + b)));
    return;
  }
  if (bid < 2560) {  // line-graph neighbor lists: 4 query edges/block
    __shared__ int sL[N_EDGES];
    __shared__ int dL[N_EDGES];
    __shared__ int cnt[4];
    int bq = bid - 1536;
#pragma unroll
    for (int i = 0; i < 16; i++) {
      int j = i * 256 + tid;
      sL[j] = src[j];
      dL[j] = dst[j];
    }
    if (tid < 4) cnt[tid] = 0;
    __syncthreads();
    int w = tid >> 6, lane = tid & 63;
    int qi = bq * 4 + w;
    int sq = sL[qi], dq = dL[qi];
    for (int j = lane; j < N_EDGES; j += 64) {
      int sj = sL[j], dj = dL[j];
      if (sj == sq || sj == dq || dj == sq || dj == dq) {
        int pos = atomicAdd(&cnt[w], 1);
        if (pos < NBR_CAP) nbr[(size_t)qi * NBR_CAP + pos] = j;
      }
    }
    __syncthreads();
    if (tid < 4) deg[bq * 4 + tid] = min(cnt[tid], NBR_CAP);
    return;
  }
  if (bid < 2564) {  // W_fused = wo_n @ w_ne, 64x64 tiles
    __shared__ float As[16][68];
    __shared__ float Bs[16][68];
    int idx = bid - 2560;
    int bm = (idx >> 1) * 64, bn = (idx & 1) * 64;
    int tm = (tid >> 4) * 4, tn = (tid & 15) * 4;
    float4 acc[4] = {{0,0,0,0},{0,0,0,0},{0,0,0,0},{0,0,0,0}};
    for (int k0 = 0; k0 < DIM; k0 += 16) {
#pragma unroll
      for (int i = 0; i < 4; i++) {
        int e = i * 256 + tid;
        int r = e >> 4, kk = e & 15;
        As[kk][r] = wo_n[(size_t)(bm + r) * DIM + k0 + kk];
        int kb = e >> 6, c = e & 63;
        Bs[kb][c] = w_ne[(size_t)(k0 + kb) * DIM + bn + c];
      }
      __syncthreads();
#pragma unroll
      for (int kk = 0; kk < 16; kk++) {
        float4 a = *(const float4*)&As[kk][tm];
        float4 b = *(const float4*)&Bs[kk][tn];
        FMA4(acc[0], a.x, b); FMA4(acc[1], a.y, b);
        FMA4(acc[2], a.z, b); FMA4(acc[3], a.w, b);
      }
      __syncthreads();
    }
#pragma unroll
    for (int i = 0; i < 4; i++)
      *(float4*)&wfu[(size_t)(bm + tm + i) * DIM + bn + tn] = acc[i];
    return;
  }
  // b_fused = 2*(bo_n @ w_ne) + b_ne ; zero the 256 split-K counters
  acnt[tid] = 0;  // d_ws is poisoned 0xAA before timing; re-init every call
  if (tid < DIM) {
    float a = 0.f;
    for (int k = 0; k < DIM; k++)
      a = fmaf(bo_n[k], w_ne[(size_t)k * DIM + tid], a);
    bfu[tid] = 2.f * a + b_ne[tid];
  }
}

// ============ 128x64 GEMM body, bank-conflict-free A reads (g4 / g4+64) ====
typedef float As128T[16][136];
typedef float Bs68T[16][68];
__device__ __forceinline__ void gemm_body128(
    As128T& As, Bs68T& Bs, const float* __restrict__ A,
    const float* __restrict__ B, const float* gs, int bm, int bn, int K,
    int N, float4 (&acc)[8], int tid) {
  int g4 = (tid >> 4) * 4, tn = (tid & 15) * 4;
  for (int k0 = 0; k0 < K; k0 += 16) {
#pragma unroll
    for (int i = 0; i < 8; i++) {
      int e = i * 256 + tid;
      int r = e >> 4, kk = e & 15;
      float a = A[(size_t)(bm + r) * K + k0 + kk];
      As[kk][r] = gs ? a * gs[r] : a;
    }
#pragma unroll
    for (int i = 0; i < 4; i++) {
      int e = i * 256 + tid;
      int kb = e >> 6, c = e & 63;
      Bs[kb][c] = B[(size_t)(k0 + kb) * N + bn + c];
    }
    __syncthreads();
#pragma unroll
    for (int kk = 0; kk < 16; kk++) {
      float4 a0 = *(const float4*)&As[kk][g4];
      float4 a1 = *(const float4*)&As[kk][g4 + 64];
      float4 b = *(const float4*)&Bs[kk][tn];
      FMA4(acc[0], a0.x, b); FMA4(acc[1], a0.y, b);
      FMA4(acc[2], a0.z, b); FMA4(acc[3], a0.w, b);
      FMA4(acc[4], a1.x, b); FMA4(acc[5], a1.y, b);
      FMA4(acc[6], a1.z, b); FMA4(acc[7], a1.w, b);
    }
    __syncthreads();
  }
}

// ============ K2: topk (block 0) + six QKV GEMM tiles (1..288) ==============
__global__ __launch_bounds__(256) void topk_qkv_kernel(
    const float* __restrict__ nf, const float* __restrict__ ef,
    const float* __restrict__ ns, const float* __restrict__ es,
    const float* __restrict__ wq_n, const float* __restrict__ wk_n,
    const float* __restrict__ wv_n, const float* __restrict__ wq_e,
    const float* __restrict__ wk_e, const float* __restrict__ wv_e,
    const float* __restrict__ bq_n, const float* __restrict__ bk_n,
    const float* __restrict__ bv_n, const float* __restrict__ bq_e,
    const float* __restrict__ bk_e, const float* __restrict__ bv_e,
    float* __restrict__ qn, float* __restrict__ kn, float* __restrict__ vn,
    float* __restrict__ qe, float* __restrict__ ke, float* __restrict__ ve,
    int* __restrict__ kidx, int* __restrict__ nkept) {
  __shared__ float As[16][136];
  __shared__ float Bs[16][68];
  __shared__ float ss[128];
  __shared__ unsigned sh_lo;
  __shared__ int wcnt;
  int tid = threadIdx.x;
  if (blockIdx.x == 0) {
    // kth largest = max{v : count(s>=v) >= k}; single-wave binary search on
    // float bits (sigmoid in (0,1) -> bit order == value order; 64-bit
    // midpoint: u32 overflow hung round 1).
    if (tid == 0) wcnt = 0;
    if (tid < 64) {
      unsigned bv[32];
#pragma unroll
      for (int i = 0; i < 32; i++) bv[i] = __float_as_uint(ns[tid * 32 + i]);
      unsigned lo = 0u, hi = 0x3F800000u;  // scores < 1.0f
      while (lo < hi) {
        unsigned mid = (unsigned)(((unsigned long long)lo + hi + 1ull) >> 1);
        int c = 0;
#pragma unroll
        for (int i = 0; i < 32; i++) c += (bv[i] >= mid);
#pragma unroll
        for (int o = 1; o < 64; o <<= 1) c += __shfl_xor(c, o, 64);
        if (c >= TOPK) lo = mid; else hi = mid - 1;
      }
      if (tid == 0) sh_lo = lo;
    }
    __syncthreads();
    unsigned lo = sh_lo;
#pragma unroll
    for (int i = 0; i < 8; i++) {
      int idx = tid * 8 + i;
      if (__float_as_uint(ns[idx]) >= lo) kidx[atomicAdd(&wcnt, 1)] = idx;
    }
    __syncthreads();
    if (tid == 0) nkept[0] = wcnt;
    return;
  }
  int bx = blockIdx.x - 1;  // 0..287
  bool edge = bx >= 96;
  int mat, bm, bn;
  const float* A;
  const float* sc;
  if (!edge) {
    mat = bx / 32;
    int rem = bx % 32;
    bm = (rem >> 1) * 128;
    bn = (rem & 1) * 64;
    A = nf; sc = ns;
  } else {
    int be = bx - 96;
    mat = be / 64;
    int rem = be % 64;
    bm = (rem >> 1) * 128;
    bn = (rem & 1) * 64;
    A = ef; sc = es;
  }
  const float* W;
  const float* bias;
  float* C;
  if (!edge) {
    if (mat == 0) { W = wq_n; bias = bq_n; C = qn; }
    else if (mat == 1) { W = wk_n; bias = bk_n; C = kn; }
    else { W = wv_n; bias = bv_n; C = vn; }
  } else {
    if (mat == 0) { W = wq_e; bias = bq_e; C = qe; }
    else if (mat == 1) { W = wk_e; bias = bk_e; C = ke; }
    else { W = wv_e; bias = bv_e; C = ve; }
  }
  if (tid < 128) ss[tid] = sc[bm + tid];
  __syncthreads();
  float4 acc[8] = {{0,0,0,0},{0,0,0,0},{0,0,0,0},{0,0,0,0},
                   {0,0,0,0},{0,0,0,0},{0,0,0,0},{0,0,0,0}};
  gemm_body128(As, Bs, A, W, ss, bm, bn, DIM, DIM, acc, tid);
  int g4 = (tid >> 4) * 4, tn = (tid & 15) * 4;
  float4 b4 = *(const float4*)&bias[bn + tn];
#pragma unroll
  for (int i = 0; i < 4; i++) {
    float4 r;
    r.x = acc[i].x + b4.x; r.y = acc[i].y + b4.y;
    r.z = acc[i].z + b4.z; r.w = acc[i].w + b4.w;
    *(float4*)&C[(size_t)(bm + g4 + i) * DIM + bn + tn] = r;
  }
#pragma unroll
  for (int i = 0; i < 4; i++) {
    float4 r;
    r.x = acc[4 + i].x + b4.x; r.y = acc[4 + i].y + b4.y;
    r.z = acc[4 + i].z + b4.z; r.w = acc[4 + i].w + b4.w;
    *(float4*)&C[(size_t)(bm + 64 + g4 + i) * DIM + bn + tn] = r;
  }
}

// ============ K3: node attn (two-GEMM, key-split x4, blocks 0..1023;
//              LAST split-block per (q-unit, h) reduces -> aon) +
//              edge attn (blocks 1024..2047) ================================
__global__ __launch_bounds__(256) void attn_kernel(
    const float* __restrict__ Q, const float* __restrict__ K,
    const float* __restrict__ V, const int* __restrict__ kidx,
    const int* __restrict__ nkeptp, float* __restrict__ pacc,
    float* __restrict__ ps, int* __restrict__ acnt, float* __restrict__ aon,
    const float* __restrict__ Qe, const float* __restrict__ Ke,
    const float* __restrict__ Ve, const int* __restrict__ nbr,
    const int* __restrict__ deg, float* __restrict__ Oe) {
  __shared__ float Qs[32][36];  // [d][q] transposed
  __shared__ float Ks[64][36];  // [k][d]
  __shared__ float Vs[64][36];  // [k][d]
  __shared__ float Ps[32][68];  // [q][k]
  __shared__ int isLast;
  int tid = threadIdx.x;
  int bid = blockIdx.x;
  if (bid < 1024) {
    int bxa = bid & 63;
    int h = (bid >> 6) & 3;
    int sp = bid >> 8;
    int grp = bid & 255;  // (h, bxa) unique, split-independent
    int qbase = bxa * QB;
    int nkept = nkeptp[0];
    int spl = (nkept + NSPLIT - 1) / NSPLIT;
    int start = sp * spl;
    int end = min(start + spl, nkept);

    // stage Q transposed: thread (q8 = tid>>3, d8 = tid&7)
    {
      int q8 = tid >> 3, d8 = tid & 7;
      const float4* qp =
          (const float4*)(Q + (size_t)(qbase + q8) * DIM + h * DH) + d8;
      float4 qv = *qp;
      Qs[d8 * 4 + 0][q8] = qv.x;
      Qs[d8 * 4 + 1][q8] = qv.y;
      Qs[d8 * 4 + 2][q8] = qv.z;
      Qs[d8 * 4 + 3][q8] = qv.w;
    }

    int tq = tid >> 5;          // 0..7 (GEMM1 q-group)
    int tk = tid & 31;          // GEMM1: keys tk, tk+32
    int kg = tid >> 6;          // GEMM2: key quarter (16 keys)
    int tq2 = (tid >> 3) & 7;   // GEMM2: q-group
    int td4 = tid & 7;          // GEMM2: d-quad
    float4 o4[4] = {{0,0,0,0},{0,0,0,0},{0,0,0,0},{0,0,0,0}};
    float sump[4] = {0.f, 0.f, 0.f, 0.f};

    for (int t0 = start; t0 < end; t0 += 64) {
#pragma unroll
      for (int i = 0; i < 2; i++) {
        int id = i * 256 + tid;
        int r = id >> 3, c4 = id & 7;
        int row = t0 + r;
        int ki = (row < end) ? kidx[row] : kidx[0];
        const float4* kp = (const float4*)(K + (size_t)ki * DIM + h * DH) + c4;
        const float4* vp = (const float4*)(V + (size_t)ki * DIM + h * DH) + c4;
        *(float4*)&Ks[r][c4 * 4] = *kp;
        *(float4*)&Vs[r][c4 * 4] = *vp;
      }
      __syncthreads();
      // GEMM1: s[q 4][k 2] over 32 dims
      float4 s0v = {0.f, 0.f, 0.f, 0.f};  // k = tk
      float4 s1v = {0.f, 0.f, 0.f, 0.f};  // k = tk+32
#pragma unroll
      for (int kk4 = 0; kk4 < 8; kk4++) {
        int kk = kk4 * 4;
        float4 ka = *(const float4*)&Ks[tk][kk];
        float4 kb = *(const float4*)&Ks[tk + 32][kk];
        float4 qa = *(const float4*)&Qs[kk + 0][tq * 4];
        float4 qb = *(const float4*)&Qs[kk + 1][tq * 4];
        float4 qc = *(const float4*)&Qs[kk + 2][tq * 4];
        float4 qd = *(const float4*)&Qs[kk + 3][tq * 4];
        FMA4(s0v, ka.x, qa); FMA4(s0v, ka.y, qb);
        FMA4(s0v, ka.z, qc); FMA4(s0v, ka.w, qd);
        FMA4(s1v, kb.x, qa); FMA4(s1v, kb.y, qb);
        FMA4(s1v, kb.z, qc); FMA4(s1v, kb.w, qd);
      }
      // batched exp (scores tiny -> no running max), P write, sum partials
      bool va = (t0 + tk) < end;
      bool vb = (t0 + tk + 32) < end;
      float p00 = va ? __expf(s0v.x * SCALE) : 0.f;
      float p01 = va ? __expf(s0v.y * SCALE) : 0.f;
      float p02 = va ? __expf(s0v.z * SCALE) : 0.f;
      float p03 = va ? __expf(s0v.w * SCALE) : 0.f;
      float p10 = vb ? __expf(s1v.x * SCALE) : 0.f;
      float p11 = vb ? __expf(s1v.y * SCALE) : 0.f;
      float p12 = vb ? __expf(s1v.z * SCALE) : 0.f;
      float p13 = vb ? __expf(s1v.w * SCALE) : 0.f;
      Ps[tq * 4 + 0][tk] = p00;      Ps[tq * 4 + 1][tk] = p01;
      Ps[tq * 4 + 2][tk] = p02;      Ps[tq * 4 + 3][tk] = p03;
      Ps[tq * 4 + 0][tk + 32] = p10; Ps[tq * 4 + 1][tk + 32] = p11;
      Ps[tq * 4 + 2][tk + 32] = p12; Ps[tq * 4 + 3][tk + 32] = p13;
      sump[0] += p00 + p10;
      sump[1] += p01 + p11;
      sump[2] += p02 + p12;
      sump[3] += p03 + p13;
      __syncthreads();
      // GEMM2: o[q 4][d 4] += P[q][k] * V[k][d] over this thread's 16 keys
#pragma unroll
      for (int k4 = 0; k4 < 4; k4++) {
        int kb = kg * 16 + k4 * 4;
        float4 p0 = *(const float4*)&Ps[tq2 * 4 + 0][kb];
        float4 p1 = *(const float4*)&Ps[tq2 * 4 + 1][kb];
        float4 p2 = *(const float4*)&Ps[tq2 * 4 + 2][kb];
        float4 p3 = *(const float4*)&Ps[tq2 * 4 + 3][kb];
        float4 v0 = *(const float4*)&Vs[kb + 0][td4 * 4];
        float4 v1 = *(const float4*)&Vs[kb + 1][td4 * 4];
        float4 v2 = *(const float4*)&Vs[kb + 2][td4 * 4];
        float4 v3 = *(const float4*)&Vs[kb + 3][td4 * 4];
        FMA4(o4[0], p0.x, v0); FMA4(o4[0], p0.y, v1);
        FMA4(o4[0], p0.z, v2); FMA4(o4[0], p0.w, v3);
        FMA4(o4[1], p1.x, v0); FMA4(o4[1], p1.y, v1);
        FMA4(o4[1], p1.z, v2); FMA4(o4[1], p1.w, v3);
        FMA4(o4[2], p2.x, v0); FMA4(o4[2], p2.y, v1);
        FMA4(o4[2], p2.z, v2); FMA4(o4[2], p2.w, v3);
        FMA4(o4[3], p3.x, v0); FMA4(o4[3], p3.y, v1);
        FMA4(o4[3], p3.z, v2); FMA4(o4[3], p3.w, v3);
      }
      __syncthreads();
    }
    // reduce sump over the 32 tk lanes (half-wave, matches tq grouping)
#pragma unroll
    for (int os = 1; os < 32; os <<= 1) {
#pragma unroll
      for (int j = 0; j < 4; j++) sump[j] += __shfl_xor(sump[j], os, 64);
    }
    if (tk == 0) {
#pragma unroll
      for (int j = 0; j < 4; j++) {
        int q = qbase + tq * 4 + j;
        size_t idx = ((size_t)q * HEADS + h) * NSPLIT + sp;
        ps[idx] = sump[j];
      }
    }
    // reduce o4 across the 4 kg groups via scratch carved from Ks/Vs
    float* scrA = &Ks[0][0];  // j = 0,1
    float* scrB = &Vs[0][0];  // j = 2,3
    int slot = (kg * 64 + tq2 * 8 + td4) * 8;
    *(float4*)&scrA[slot + 0] = o4[0];
    *(float4*)&scrA[slot + 4] = o4[1];
    *(float4*)&scrB[slot + 0] = o4[2];
    *(float4*)&scrB[slot + 4] = o4[3];
    __syncthreads();
    {
      int qq = tid >> 3;       // 0..31
      int d4 = tid & 7;        // 0..7
      int tqr = qq >> 2, j = qq & 3;
      const float* bank = (j < 2) ? scrA : scrB;
      int off = (j & 1) * 4;
      float4 of = {0.f, 0.f, 0.f, 0.f};
#pragma unroll
      for (int g = 0; g < 4; g++) {
        float4 part =
            *(const float4*)&bank[(g * 64 + tqr * 8 + d4) * 8 + off];
        of.x += part.x; of.y += part.y; of.z += part.z; of.w += part.w;
      }
      size_t idx = ((size_t)(qbase + qq) * HEADS + h) * NSPLIT + sp;
      *(float4*)&pacc[idx * 32 + d4 * 4] = of;
    }
    // ---- split-K finalize: last block of the 4 splits reduces -> aon ----
    __syncthreads();  // all partial stores issued block-wide
    if (tid == 0) {
      __threadfence();  // make pacc/ps visible device-wide before count
      int old = atomicAdd(&acnt[grp], 1);
      isLast = (old == NSPLIT - 1);
    }
    __syncthreads();
    if (!isLast) return;
    __threadfence();  // acquire: see other splits' pacc/ps
#pragma unroll
    for (int i = 0; i < 4; i++) {
      int e = i * 256 + tid;   // 0..1023 = 32q x 32d
      int qq = e >> 5, d = e & 31;
      int q = qbase + qq;
      float ssum = 0.f, v = 0.f;
#pragma unroll
      for (int s2 = 0; s2 < NSPLIT; s2++) {
        size_t idx = ((size_t)q * HEADS + h) * NSPLIT + s2;
        ssum += ps[idx];
        v += pacc[idx * 32 + d];
      }
      aon[(size_t)q * DIM + h * DH + d] = v / ssum;
    }
    if (tid == 0) acnt[grp] = 0;  // leave zeroed for next graph replay
    return;
  }
  // edge attention: 4 query edges/block; wave = head;
  // lane = (q 2b | nbr-slot 2b | dim-qtr 2b)
  int h = tid >> 6;
  int lane = tid & 63;
  int ql = lane >> 4, j4 = (lane >> 2) & 3, g = lane & 3;
  int qi = (bid - 1024) * 4 + ql;
  int dg = deg[qi];
  const float4* qp = (const float4*)(Qe + (size_t)qi * DIM + h * DH + g * 8);
  float4 q0 = qp[0], q1 = qp[1];
  float s = 0.f;
  float4 a0 = make_float4(0.f, 0.f, 0.f, 0.f);
  float4 a1 = make_float4(0.f, 0.f, 0.f, 0.f);
  for (int c0 = 0; c0 < dg; c0 += 4) {
    int j = c0 + j4;
    bool act = j < dg;
    int ei = act ? nbr[(size_t)qi * NBR_CAP + j] : 0;
    const float4* kp = (const float4*)(Ke + (size_t)ei * DIM + h * DH + g * 8);
    float4 k0 = kp[0], k1 = kp[1];
    float pd = q0.x * k0.x + q0.y * k0.y + q0.z * k0.z + q0.w * k0.w +
               q1.x * k1.x + q1.y * k1.y + q1.z * k1.z + q1.w * k1.w;
    pd += __shfl_xor(pd, 1, 64);
    pd += __shfl_xor(pd, 2, 64);  // full 32-dot in all 4 dim-qtr lanes
    float pr = act ? __expf(pd * SCALE) : 0.f;
    s += pr;
    const float4* vp = (const float4*)(Ve + (size_t)ei * DIM + h * DH + g * 8);
    float4 v0 = vp[0], v1 = vp[1];
    FMA4(a0, pr, v0);
    FMA4(a1, pr, v1);
  }
#pragma unroll
  for (int o = 4; o <= 8; o <<= 1) {
    s += __shfl_xor(s, o, 64);
    a0.x += __shfl_xor(a0.x, o, 64); a0.y += __shfl_xor(a0.y, o, 64);
    a0.z += __shfl_xor(a0.z, o, 64); a0.w += __shfl_xor(a0.w, o, 64);
    a1.x += __shfl_xor(a1.x, o, 64); a1.y += __shfl_xor(a1.y, o, 64);
    a1.z += __shfl_xor(a1.z, o, 64); a1.w += __shfl_xor(a1.w, o, 64);
  }
  if (j4 == 0) {
    float inv = 1.0f / s;
    float4* op = (float4*)(Oe + (size_t)qi * DIM + h * DH + g * 8);
    float4 r0 = {a0.x * inv, a0.y * inv, a0.z * inv, a0.w * inv};
    float4 r1 = {a1.x * inv, a1.y * inv, a1.z * inv, a1.w * inv};
    op[0] = r0;
    op[1] = r1;
  }
}

// ============ K4: per 8 edge-rows: ue = aoe@wo_e + (aonS+aonD)@W_fused
//   + (bo_e + b_fused); h = gelu(ue @ w_c1 + b_c1); out = h @ w_c2 + b_c2 ===
__global__ __launch_bounds__(256) void tail_kernel(
    const float* __restrict__ aoe, const float* __restrict__ wo_e,
    const float* __restrict__ bo_e, const float* __restrict__ aon,
    const int* __restrict__ src, const int* __restrict__ dst,
    const float* __restrict__ wfu, const float* __restrict__ bfu,
    const float* __restrict__ w_c1, const float* __restrict__ b_c1,
    const float* __restrict__ w_c2, const float* __restrict__ b_c2,
    float* __restrict__ out) {
  // LDS: ue_s[8][132] @0 (4224) | As0[16][12] @4224 (768) |
  //      Bs[16][132] @4992 (8448) ; phase B: Bs2[16][264] @4224 (16896)
  //      phase C: wT[16][260] @4224 (16640, reuses Bs2 region)
  __shared__ __align__(16) char smem[21120];
  float (*ue_s)[132] = (float(*)[132])smem;
  float (*As0)[12] = (float(*)[12])(smem + 4224);
  float (*Bs)[132] = (float(*)[132])(smem + 4992);
  float (*Bs2)[264] = (float(*)[264])(smem + 4224);
  float* wT = (float*)(smem + 4224);  // [16 cols][260] (k stride 1)
  int tid = threadIdx.x;
  int bm = blockIdx.x * 8;
  int tr = tid >> 5;          // 1 row per thread
  int tn = (tid & 31) * 4;    // 4 cols (of 128)
  float4 acc = {0, 0, 0, 0};
  // ---- GEMM 1: aoe rows @ wo_e ----
  for (int k0 = 0; k0 < DIM; k0 += 16) {
    if (tid < 128) {
      int r = tid >> 4, kk = tid & 15;
      As0[kk][r] = aoe[(size_t)(bm + r) * DIM + k0 + kk];
    }
#pragma unroll
    for (int i = 0; i < 8; i++) {
      int id = i * 256 + tid;
      int kb = id >> 7, c = id & 127;
      Bs[kb][c] = wo_e[(size_t)(k0 + kb) * DIM + c];
    }
    __syncthreads();
#pragma unroll
    for (int kk = 0; kk < 16; kk++) {
      float a = As0[kk][tr];
      float4 b = *(const float4*)&Bs[kk][tn];
      FMA4(acc, a, b);
    }
    __syncthreads();
  }
  // ---- GEMM 2 (accumulate): (aon[src]+aon[dst]) rows @ W_fused ----
  for (int k0 = 0; k0 < DIM; k0 += 16) {
    if (tid < 128) {
      int r = tid >> 4, kk = tid & 15;
      int row = bm + r;
      int s0 = src[row], d0 = dst[row];
      As0[kk][r] = aon[(size_t)s0 * DIM + k0 + kk] +
                   aon[(size_t)d0 * DIM + k0 + kk];
    }
#pragma unroll
    for (int i = 0; i < 8; i++) {
      int id = i * 256 + tid;
      int kb = id >> 7, c = id & 127;
      Bs[kb][c] = wfu[(size_t)(k0 + kb) * DIM + c];
    }
    __syncthreads();
#pragma unroll
    for (int kk = 0; kk < 16; kk++) {
      float a = As0[kk][tr];
      float4 b = *(const float4*)&Bs[kk][tn];
      FMA4(acc, a, b);
    }
    __syncthreads();
  }
  // ---- ue = acc + bo_e + b_fused -> LDS ----
  {
    float4 be = *(const float4*)&bo_e[tn];
    float4 bf = *(const float4*)&bfu[tn];
    float4 r;
    r.x = acc.x + be.x + bf.x; r.y = acc.y + be.y + bf.y;
    r.z = acc.z + be.z + bf.z; r.w = acc.w + be.w + bf.w;
    *(float4*)&ue_s[tr][tn] = r;
  }
  __syncthreads();
  // ---- GEMM 3: h = gelu(ue @ w_c1 + b_c1), 8x256, h kept in registers ----
  int c4 = (tid & 31) * 4;  // cols c4 and c4+128
  float4 acc2[2] = {{0,0,0,0},{0,0,0,0}};
  for (int k0 = 0; k0 < DIM; k0 += 16) {
#pragma unroll
    for (int i = 0; i < 16; i++) {
      int id = i * 256 + tid;
      int kb = id >> 8, c = id & 255;
      Bs2[kb][c] = w_c1[(size_t)(k0 + kb) * 256 + c];
    }
    __syncthreads();
#pragma unroll
    for (int kk = 0; kk < 16; kk++) {
      float av = ue_s[tr][k0 + kk];
      float4 bva = *(const float4*)&Bs2[kk][c4];
      float4 bvb = *(const float4*)&Bs2[kk][c4 + 128];
      FMA4(acc2[0], av, bva);
      FMA4(acc2[1], av, bvb);
    }
    __syncthreads();
  }
  float hv[2][4];
  {
    float4 bc0 = *(const float4*)&b_c1[c4];
    float4 bc1 = *(const float4*)&b_c1[c4 + 128];
#pragma unroll
    for (int half = 0; half < 2; half++) {
      float4 bb = half ? bc1 : bc0;
      float4 av = acc2[half];
      float vv[4] = {av.x + bb.x, av.y + bb.y, av.z + bb.z, av.w + bb.w};
#pragma unroll
      for (int j = 0; j < 4; j++) {
        float v = vv[j];
        float u = 0.7978845608028654f * (v + 0.044715f * v * v * v);
        hv[half][j] = 0.5f * v * (1.0f + tanhf(u));
      }
    }
  }
  // ---- out = h @ w_c2 + b_c2 : stage w_c2 transposed, dot, butterfly ----
  __syncthreads();  // Bs2 dead -> wT
#pragma unroll
  for (int i = 0; i < 4; i++) {
    int id = i * 256 + tid;  // fl4 index into w_c2 [256][16]
    float4 w4 = ((const float4*)w_c2)[id];
    int k = id >> 2, cc = (id & 3) * 4;
    wT[(cc + 0) * 260 + k] = w4.x;
    wT[(cc + 1) * 260 + k] = w4.y;
    wT[(cc + 2) * 260 + k] = w4.z;
    wT[(cc + 3) * 260 + k] = w4.w;
  }
  __syncthreads();
  float oacc[NCLS];
#pragma unroll
  for (int c = 0; c < NCLS; c++) {
    float4 wa = *(const float4*)&wT[c * 260 + c4];
    float4 wb = *(const float4*)&wT[c * 260 + c4 + 128];
    float v = hv[0][0] * wa.x;
    v = fmaf(hv[0][1], wa.y, v);
    v = fmaf(hv[0][2], wa.z, v);
    v = fmaf(hv[0][3], wa.w, v);
    v = fmaf(hv[1][0], wb.x, v);
    v = fmaf(hv[1][1], wb.y, v);
    v = fmaf(hv[1][2], wb.z, v);
    v = fmaf(hv[1][3], wb.w, v);
    oacc[c] = v;
  }
  // butterfly over the row's 32 contiguous lanes (offsets <=16 stay in-row)
#pragma unroll
  for (int os = 1; os < 32; os <<= 1) {
#pragma unroll
    for (int c = 0; c < NCLS; c++) oacc[c] += __shfl_xor(oacc[c], os, 64);
  }
  if ((tid & 31) < NCLS) {
    int col = tid & 15;
    out[(size_t)(bm + tr) * NCLS + col] = oacc[col] + b_c2[col];
  }
}

extern "C" void kernel_launch(void* const* d_in, const int* in_sizes, int n_in,
                              void* d_out, int out_size, void* d_ws,
                              size_t ws_size, hipStream_t stream) {
  const float* nf = (const float*)d_in[0];
  const float* ef = (const float*)d_in[1];
  const int* ei = (const int*)d_in[2];
  const float* w_rn = (const float*)d_in[3];
  const float* b_rn = (const float*)d_in[4];
  const float* w_re = (const float*)d_in[5];
  const float* b_re = (const float*)d_in[6];
  const float* wq_n = (const float*)d_in[7];
  const float* bq_n = (const float*)d_in[8];
  const float* wk_n = (const float*)d_in[9];
  const float* bk_n = (const float*)d_in[10];
  const float* wv_n = (const float*)d_in[11];
  const float* bv_n = (const float*)d_in[12];
  const float* wo_n = (const float*)d_in[13];
  const float* bo_n = (const float*)d_in[14];
  const float* wq_e = (const float*)d_in[15];
  const float* bq_e = (const float*)d_in[16];
  const float* wk_e = (const float*)d_in[17];
  const float* bk_e = (const float*)d_in[18];
  const float* wv_e = (const float*)d_in[19];
  const float* bv_e = (const float*)d_in[20];
  const float* wo_e = (const float*)d_in[21];
  const float* bo_e = (const float*)d_in[22];
  const float* w_ne = (const float*)d_in[23];
  const float* b_ne = (const float*)d_in[24];
  const float* w_c1 = (const float*)d_in[25];
  const float* b_c1 = (const float*)d_in[26];
  const float* w_c2 = (const float*)d_in[27];
  const float* b_c2 = (const float*)d_in[28];

  const int* src = ei;
  const int* dst = ei + N_EDGES;

  float* ws = (float*)d_ws;
  size_t o = 0;
  float* ns = ws + o;   o += 2048;
  float* es = ws + o;   o += 4096;
  int* kidx = (int*)(ws + o); o += 2048;
  int* nkept = (int*)(ws + o); o += 64;
  int* nbr = (int*)(ws + o); o += (size_t)N_EDGES * NBR_CAP;
  int* degp = (int*)(ws + o); o += N_EDGES;
  float* wfu = ws + o;  o += DIM * DIM;
  float* bfu = ws + o;  o += DIM;
  float* qn = ws + o;   o += (size_t)N_NODES * DIM;
  float* kn = ws + o;   o += (size_t)N_NODES * DIM;
  float* vn = ws + o;   o += (size_t)N_NODES * DIM;
  float* qe = ws + o;   o += (size_t)N_EDGES * DIM;
  float* ke = ws + o;   o += (size_t)N_EDGES * DIM;
  float* ve = ws + o;   o += (size_t)N_EDGES * DIM;
  float* aon = ws + o;  o += (size_t)N_NODES * DIM;
  float* aoe = ws + o;  o += (size_t)N_EDGES * DIM;
  float* pacc = ws + o; o += (size_t)N_NODES * HEADS * NSPLIT * DH;
  float* ps = ws + o;   o += (size_t)N_NODES * HEADS * NSPLIT;
  int* acnt = (int*)(ws + o); o += 256;

  // K1: scores + nbr lists + W_fused/b_fused + counter zero (all independent)
  prep_kernel<<<dim3(2565), 256, 0, stream>>>(
      nf, ef, w_rn, b_rn, w_re, b_re, src, dst, wo_n, bo_n, w_ne, b_ne,
      ns, es, nbr, degp, wfu, bfu, acnt);
  // K2: topk + six QKV projections (gating fused into A-stage)
  topk_qkv_kernel<<<dim3(289), 256, 0, stream>>>(
      nf, ef, ns, es, wq_n, wk_n, wv_n, wq_e, wk_e, wv_e,
      bq_n, bk_n, bv_n, bq_e, bk_e, bv_e, qn, kn, vn, qe, ke, ve,
      kidx, nkept);
  // K3: node attention (split-K x4, last block reduces -> aon) + edge attn
  attn_kernel<<<dim3(2048), 256, 0, stream>>>(
      qn, kn, vn, kidx, nkept, pacc, ps, acnt, aon, qe, ke, ve, nbr, degp,
      aoe);
  // K4: ue -> gelu -> out (single fused tail, writes d_out)
  tail_kernel<<<dim3(N_EDGES / 8), 256, 0, stream>>>(
      aoe, wo_e, bo_e, aon, src, dst, wfu, bfu, w_c1, b_c1, w_c2, b_c2,
      (float*)d_out);
}

// Round 16
// 128.634 us; speedup vs baseline: 1.4525x; 1.4525x over previous
//
#include <hip/hip_runtime.h>
#include <math.h>

#define N_NODES 2048
#define N_EDGES 4096
#define DIM 128
#define HEADS 4
#define DH 32
#define NCLS 16
#define TOPK 1024
#define NBR_CAP 64
#define NSPLIT 4
#define QB 32  // queries per attn_node unit
#define SCALE 0.17677669529663687f  // 1/sqrt(32)

#define FMA4(ACC, AS, BV)                                       \
  ACC.x = fmaf(AS, BV.x, ACC.x); ACC.y = fmaf(AS, BV.y, ACC.y); \
  ACC.z = fmaf(AS, BV.z, ACC.z); ACC.w = fmaf(AS, BV.w, ACC.w)

__device__ __forceinline__ float wave_reduce_sum(float v) {
#pragma unroll
  for (int o = 32; o > 0; o >>= 1) v += __shfl_xor(v, o, 64);
  return v;
}

// ============ K1: scores (0..1535) + nbr lists (1536..2559, 4 q/block) +
//              W_fused (2560..2563) + b_fused (2564) ========================
__global__ __launch_bounds__(256) void prep_kernel(
    const float* __restrict__ nf, const float* __restrict__ ef,
    const float* __restrict__ w_rn, const float* __restrict__ b_rn,
    const float* __restrict__ w_re, const float* __restrict__ b_re,
    const int* __restrict__ src, const int* __restrict__ dst,
    const float* __restrict__ wo_n, const float* __restrict__ bo_n,
    const float* __restrict__ w_ne, const float* __restrict__ b_ne,
    float* __restrict__ ns, float* __restrict__ es, int* __restrict__ nbr,
    int* __restrict__ deg, float* __restrict__ wfu, float* __restrict__ bfu) {
  int tid = threadIdx.x;
  int bid = blockIdx.x;
  if (bid < 1536) {  // router scores: 4 rows/block, 1 per wave
    int wid = tid >> 6, lane = tid & 63;
    int row = bid * 4 + wid;
    const float* feat;
    const float* w;
    float b;
    float* scp;
    if (row < N_NODES) {
      feat = nf + (size_t)row * DIM;
      w = w_rn; b = b_rn[0];
      scp = ns + row;
    } else {
      int r = row - N_NODES;
      feat = ef + (size_t)r * DIM;
      w = w_re; b = b_re[0];
      scp = es + r;
    }
    float d = feat[lane] * w[lane] + feat[lane + 64] * w[lane + 64];
    d = wave_reduce_sum(d);
    if (lane == 0) *scp = 1.0f / (1.0f + __expf(-(d + b)));
    return;
  }
  if (bid < 2560) {  // line-graph neighbor lists: 4 query edges/block
    __shared__ int sL[N_EDGES];
    __shared__ int dL[N_EDGES];
    __shared__ int cnt[4];
    int bq = bid - 1536;
#pragma unroll
    for (int i = 0; i < 16; i++) {
      int j = i * 256 + tid;
      sL[j] = src[j];
      dL[j] = dst[j];
    }
    if (tid < 4) cnt[tid] = 0;
    __syncthreads();
    int w = tid >> 6, lane = tid & 63;
    int qi = bq * 4 + w;
    int sq = sL[qi], dq = dL[qi];
    for (int j = lane; j < N_EDGES; j += 64) {
      int sj = sL[j], dj = dL[j];
      if (sj == sq || sj == dq || dj == sq || dj == dq) {
        int pos = atomicAdd(&cnt[w], 1);
        if (pos < NBR_CAP) nbr[(size_t)qi * NBR_CAP + pos] = j;
      }
    }
    __syncthreads();
    if (tid < 4) deg[bq * 4 + tid] = min(cnt[tid], NBR_CAP);
    return;
  }
  if (bid < 2564) {  // W_fused = wo_n @ w_ne, 64x64 tiles
    __shared__ float As[16][68];
    __shared__ float Bs[16][68];
    int idx = bid - 2560;
    int bm = (idx >> 1) * 64, bn = (idx & 1) * 64;
    int tm = (tid >> 4) * 4, tn = (tid & 15) * 4;
    float4 acc[4] = {{0,0,0,0},{0,0,0,0},{0,0,0,0},{0,0,0,0}};
    for (int k0 = 0; k0 < DIM; k0 += 16) {
#pragma unroll
      for (int i = 0; i < 4; i++) {
        int e = i * 256 + tid;
        int r = e >> 4, kk = e & 15;
        As[kk][r] = wo_n[(size_t)(bm + r) * DIM + k0 + kk];
        int kb = e >> 6, c = e & 63;
        Bs[kb][c] = w_ne[(size_t)(k0 + kb) * DIM + bn + c];
      }
      __syncthreads();
#pragma unroll
      for (int kk = 0; kk < 16; kk++) {
        float4 a = *(const float4*)&As[kk][tm];
        float4 b = *(const float4*)&Bs[kk][tn];
        FMA4(acc[0], a.x, b); FMA4(acc[1], a.y, b);
        FMA4(acc[2], a.z, b); FMA4(acc[3], a.w, b);
      }
      __syncthreads();
    }
#pragma unroll
    for (int i = 0; i < 4; i++)
      *(float4*)&wfu[(size_t)(bm + tm + i) * DIM + bn + tn] = acc[i];
    return;
  }
  // b_fused = 2*(bo_n @ w_ne) + b_ne
  if (tid < DIM) {
    float a = 0.f;
    for (int k = 0; k < DIM; k++)
      a = fmaf(bo_n[k], w_ne[(size_t)k * DIM + tid], a);
    bfu[tid] = 2.f * a + b_ne[tid];
  }
}

// ============ 128x64 GEMM body, bank-conflict-free A reads (g4 / g4+64) ====
typedef float As128T[16][136];
typedef float Bs68T[16][68];
__device__ __forceinline__ void gemm_body128(
    As128T& As, Bs68T& Bs, const float* __restrict__ A,
    const float* __restrict__ B, const float* gs, int bm, int bn, int K,
    int N, float4 (&acc)[8], int tid) {
  int g4 = (tid >> 4) * 4, tn = (tid & 15) * 4;
  for (int k0 = 0; k0 < K; k0 += 16) {
#pragma unroll
    for (int i = 0; i < 8; i++) {
      int e = i * 256 + tid;
      int r = e >> 4, kk = e & 15;
      float a = A[(size_t)(bm + r) * K + k0 + kk];
      As[kk][r] = gs ? a * gs[r] : a;
    }
#pragma unroll
    for (int i = 0; i < 4; i++) {
      int e = i * 256 + tid;
      int kb = e >> 6, c = e & 63;
      Bs[kb][c] = B[(size_t)(k0 + kb) * N + bn + c];
    }
    __syncthreads();
#pragma unroll
    for (int kk = 0; kk < 16; kk++) {
      float4 a0 = *(const float4*)&As[kk][g4];
      float4 a1 = *(const float4*)&As[kk][g4 + 64];
      float4 b = *(const float4*)&Bs[kk][tn];
      FMA4(acc[0], a0.x, b); FMA4(acc[1], a0.y, b);
      FMA4(acc[2], a0.z, b); FMA4(acc[3], a0.w, b);
      FMA4(acc[4], a1.x, b); FMA4(acc[5], a1.y, b);
      FMA4(acc[6], a1.z, b); FMA4(acc[7], a1.w, b);
    }
    __syncthreads();
  }
}

// ============ K2: topk (block 0) + six QKV GEMM tiles (1..288) ==============
__global__ __launch_bounds__(256) void topk_qkv_kernel(
    const float* __restrict__ nf, const float* __restrict__ ef,
    const float* __restrict__ ns, const float* __restrict__ es,
    const float* __restrict__ wq_n, const float* __restrict__ wk_n,
    const float* __restrict__ wv_n, const float* __restrict__ wq_e,
    const float* __restrict__ wk_e, const float* __restrict__ wv_e,
    const float* __restrict__ bq_n, const float* __restrict__ bk_n,
    const float* __restrict__ bv_n, const float* __restrict__ bq_e,
    const float* __restrict__ bk_e, const float* __restrict__ bv_e,
    float* __restrict__ qn, float* __restrict__ kn, float* __restrict__ vn,
    float* __restrict__ qe, float* __restrict__ ke, float* __restrict__ ve,
    int* __restrict__ kidx, int* __restrict__ nkept) {
  __shared__ float As[16][136];
  __shared__ float Bs[16][68];
  __shared__ float ss[128];
  __shared__ unsigned sh_lo;
  __shared__ int wcnt;
  int tid = threadIdx.x;
  if (blockIdx.x == 0) {
    // kth largest = max{v : count(s>=v) >= k}; single-wave binary search on
    // float bits (sigmoid in (0,1) -> bit order == value order; 64-bit
    // midpoint: u32 overflow hung round 1).
    if (tid == 0) wcnt = 0;
    if (tid < 64) {
      unsigned bv[32];
#pragma unroll
      for (int i = 0; i < 32; i++) bv[i] = __float_as_uint(ns[tid * 32 + i]);
      unsigned lo = 0u, hi = 0x3F800000u;  // scores < 1.0f
      while (lo < hi) {
        unsigned mid = (unsigned)(((unsigned long long)lo + hi + 1ull) >> 1);
        int c = 0;
#pragma unroll
        for (int i = 0; i < 32; i++) c += (bv[i] >= mid);
#pragma unroll
        for (int o = 1; o < 64; o <<= 1) c += __shfl_xor(c, o, 64);
        if (c >= TOPK) lo = mid; else hi = mid - 1;
      }
      if (tid == 0) sh_lo = lo;
    }
    __syncthreads();
    unsigned lo = sh_lo;
#pragma unroll
    for (int i = 0; i < 8; i++) {
      int idx = tid * 8 + i;
      if (__float_as_uint(ns[idx]) >= lo) kidx[atomicAdd(&wcnt, 1)] = idx;
    }
    __syncthreads();
    if (tid == 0) nkept[0] = wcnt;
    return;
  }
  int bx = blockIdx.x - 1;  // 0..287
  bool edge = bx >= 96;
  int mat, bm, bn;
  const float* A;
  const float* sc;
  if (!edge) {
    mat = bx / 32;
    int rem = bx % 32;
    bm = (rem >> 1) * 128;
    bn = (rem & 1) * 64;
    A = nf; sc = ns;
  } else {
    int be = bx - 96;
    mat = be / 64;
    int rem = be % 64;
    bm = (rem >> 1) * 128;
    bn = (rem & 1) * 64;
    A = ef; sc = es;
  }
  const float* W;
  const float* bias;
  float* C;
  if (!edge) {
    if (mat == 0) { W = wq_n; bias = bq_n; C = qn; }
    else if (mat == 1) { W = wk_n; bias = bk_n; C = kn; }
    else { W = wv_n; bias = bv_n; C = vn; }
  } else {
    if (mat == 0) { W = wq_e; bias = bq_e; C = qe; }
    else if (mat == 1) { W = wk_e; bias = bk_e; C = ke; }
    else { W = wv_e; bias = bv_e; C = ve; }
  }
  if (tid < 128) ss[tid] = sc[bm + tid];
  __syncthreads();
  float4 acc[8] = {{0,0,0,0},{0,0,0,0},{0,0,0,0},{0,0,0,0},
                   {0,0,0,0},{0,0,0,0},{0,0,0,0},{0,0,0,0}};
  gemm_body128(As, Bs, A, W, ss, bm, bn, DIM, DIM, acc, tid);
  int g4 = (tid >> 4) * 4, tn = (tid & 15) * 4;
  float4 b4 = *(const float4*)&bias[bn + tn];
#pragma unroll
  for (int i = 0; i < 4; i++) {
    float4 r;
    r.x = acc[i].x + b4.x; r.y = acc[i].y + b4.y;
    r.z = acc[i].z + b4.z; r.w = acc[i].w + b4.w;
    *(float4*)&C[(size_t)(bm + g4 + i) * DIM + bn + tn] = r;
  }
#pragma unroll
  for (int i = 0; i < 4; i++) {
    float4 r;
    r.x = acc[4 + i].x + b4.x; r.y = acc[4 + i].y + b4.y;
    r.z = acc[4 + i].z + b4.z; r.w = acc[4 + i].w + b4.w;
    *(float4*)&C[(size_t)(bm + 64 + g4 + i) * DIM + bn + tn] = r;
  }
}

// ============ K3: node attn as two GEMMs (blocks 0..1023, key-split x4,
//              fence-free partials) + edge attn (blocks 1024..2047) =========
// Round-15 lesson: split-K finalize via device-scope fences/atomics inside
// the kernel cost ~50us (8-XCD L2 coherence drain) — the separate reduce
// kernel + CP barrier is far cheaper. Same lesson as round-9 grid.sync.
__global__ __launch_bounds__(256) void attn_kernel(
    const float* __restrict__ Q, const float* __restrict__ K,
    const float* __restrict__ V, const int* __restrict__ kidx,
    const int* __restrict__ nkeptp, float* __restrict__ pacc,
    float* __restrict__ ps,
    const float* __restrict__ Qe, const float* __restrict__ Ke,
    const float* __restrict__ Ve, const int* __restrict__ nbr,
    const int* __restrict__ deg, float* __restrict__ Oe) {
  __shared__ float Qs[32][36];  // [d][q] transposed
  __shared__ float Ks[64][36];  // [k][d]
  __shared__ float Vs[64][36];  // [k][d]
  __shared__ float Ps[32][68];  // [q][k]
  int tid = threadIdx.x;
  int bid = blockIdx.x;
  if (bid < 1024) {
    int bxa = bid & 63;
    int h = (bid >> 6) & 3;
    int sp = bid >> 8;
    int qbase = bxa * QB;
    int nkept = nkeptp[0];
    int spl = (nkept + NSPLIT - 1) / NSPLIT;
    int start = sp * spl;
    int end = min(start + spl, nkept);

    // stage Q transposed: thread (q8 = tid>>3, d8 = tid&7)
    {
      int q8 = tid >> 3, d8 = tid & 7;
      const float4* qp =
          (const float4*)(Q + (size_t)(qbase + q8) * DIM + h * DH) + d8;
      float4 qv = *qp;
      Qs[d8 * 4 + 0][q8] = qv.x;
      Qs[d8 * 4 + 1][q8] = qv.y;
      Qs[d8 * 4 + 2][q8] = qv.z;
      Qs[d8 * 4 + 3][q8] = qv.w;
    }

    int tq = tid >> 5;          // 0..7 (GEMM1 q-group)
    int tk = tid & 31;          // GEMM1: keys tk, tk+32
    int kg = tid >> 6;          // GEMM2: key quarter (16 keys)
    int tq2 = (tid >> 3) & 7;   // GEMM2: q-group
    int td4 = tid & 7;          // GEMM2: d-quad
    float4 o4[4] = {{0,0,0,0},{0,0,0,0},{0,0,0,0},{0,0,0,0}};
    float sump[4] = {0.f, 0.f, 0.f, 0.f};

    for (int t0 = start; t0 < end; t0 += 64) {
#pragma unroll
      for (int i = 0; i < 2; i++) {
        int id = i * 256 + tid;
        int r = id >> 3, c4 = id & 7;
        int row = t0 + r;
        int ki = (row < end) ? kidx[row] : kidx[0];
        const float4* kp = (const float4*)(K + (size_t)ki * DIM + h * DH) + c4;
        const float4* vp = (const float4*)(V + (size_t)ki * DIM + h * DH) + c4;
        *(float4*)&Ks[r][c4 * 4] = *kp;
        *(float4*)&Vs[r][c4 * 4] = *vp;
      }
      __syncthreads();
      // GEMM1: s[q 4][k 2] over 32 dims
      float4 s0v = {0.f, 0.f, 0.f, 0.f};  // k = tk
      float4 s1v = {0.f, 0.f, 0.f, 0.f};  // k = tk+32
#pragma unroll
      for (int kk4 = 0; kk4 < 8; kk4++) {
        int kk = kk4 * 4;
        float4 ka = *(const float4*)&Ks[tk][kk];
        float4 kb = *(const float4*)&Ks[tk + 32][kk];
        float4 qa = *(const float4*)&Qs[kk + 0][tq * 4];
        float4 qb = *(const float4*)&Qs[kk + 1][tq * 4];
        float4 qc = *(const float4*)&Qs[kk + 2][tq * 4];
        float4 qd = *(const float4*)&Qs[kk + 3][tq * 4];
        FMA4(s0v, ka.x, qa); FMA4(s0v, ka.y, qb);
        FMA4(s0v, ka.z, qc); FMA4(s0v, ka.w, qd);
        FMA4(s1v, kb.x, qa); FMA4(s1v, kb.y, qb);
        FMA4(s1v, kb.z, qc); FMA4(s1v, kb.w, qd);
      }
      // batched exp (scores tiny -> no running max), P write, sum partials
      bool va = (t0 + tk) < end;
      bool vb = (t0 + tk + 32) < end;
      float p00 = va ? __expf(s0v.x * SCALE) : 0.f;
      float p01 = va ? __expf(s0v.y * SCALE) : 0.f;
      float p02 = va ? __expf(s0v.z * SCALE) : 0.f;
      float p03 = va ? __expf(s0v.w * SCALE) : 0.f;
      float p10 = vb ? __expf(s1v.x * SCALE) : 0.f;
      float p11 = vb ? __expf(s1v.y * SCALE) : 0.f;
      float p12 = vb ? __expf(s1v.z * SCALE) : 0.f;
      float p13 = vb ? __expf(s1v.w * SCALE) : 0.f;
      Ps[tq * 4 + 0][tk] = p00;      Ps[tq * 4 + 1][tk] = p01;
      Ps[tq * 4 + 2][tk] = p02;      Ps[tq * 4 + 3][tk] = p03;
      Ps[tq * 4 + 0][tk + 32] = p10; Ps[tq * 4 + 1][tk + 32] = p11;
      Ps[tq * 4 + 2][tk + 32] = p12; Ps[tq * 4 + 3][tk + 32] = p13;
      sump[0] += p00 + p10;
      sump[1] += p01 + p11;
      sump[2] += p02 + p12;
      sump[3] += p03 + p13;
      __syncthreads();
      // GEMM2: o[q 4][d 4] += P[q][k] * V[k][d] over this thread's 16 keys
#pragma unroll
      for (int k4 = 0; k4 < 4; k4++) {
        int kb = kg * 16 + k4 * 4;
        float4 p0 = *(const float4*)&Ps[tq2 * 4 + 0][kb];
        float4 p1 = *(const float4*)&Ps[tq2 * 4 + 1][kb];
        float4 p2 = *(const float4*)&Ps[tq2 * 4 + 2][kb];
        float4 p3 = *(const float4*)&Ps[tq2 * 4 + 3][kb];
        float4 v0 = *(const float4*)&Vs[kb + 0][td4 * 4];
        float4 v1 = *(const float4*)&Vs[kb + 1][td4 * 4];
        float4 v2 = *(const float4*)&Vs[kb + 2][td4 * 4];
        float4 v3 = *(const float4*)&Vs[kb + 3][td4 * 4];
        FMA4(o4[0], p0.x, v0); FMA4(o4[0], p0.y, v1);
        FMA4(o4[0], p0.z, v2); FMA4(o4[0], p0.w, v3);
        FMA4(o4[1], p1.x, v0); FMA4(o4[1], p1.y, v1);
        FMA4(o4[1], p1.z, v2); FMA4(o4[1], p1.w, v3);
        FMA4(o4[2], p2.x, v0); FMA4(o4[2], p2.y, v1);
        FMA4(o4[2], p2.z, v2); FMA4(o4[2], p2.w, v3);
        FMA4(o4[3], p3.x, v0); FMA4(o4[3], p3.y, v1);
        FMA4(o4[3], p3.z, v2); FMA4(o4[3], p3.w, v3);
      }
      __syncthreads();
    }
    // reduce sump over the 32 tk lanes (half-wave, matches tq grouping)
#pragma unroll
    for (int os = 1; os < 32; os <<= 1) {
#pragma unroll
      for (int j = 0; j < 4; j++) sump[j] += __shfl_xor(sump[j], os, 64);
    }
    if (tk == 0) {
#pragma unroll
      for (int j = 0; j < 4; j++) {
        int q = qbase + tq * 4 + j;
        size_t idx = ((size_t)q * HEADS + h) * NSPLIT + sp;
        ps[idx] = sump[j];
      }
    }
    // reduce o4 across the 4 kg groups via scratch carved from Ks/Vs
    float* scrA = &Ks[0][0];  // j = 0,1
    float* scrB = &Vs[0][0];  // j = 2,3
    int slot = (kg * 64 + tq2 * 8 + td4) * 8;
    *(float4*)&scrA[slot + 0] = o4[0];
    *(float4*)&scrA[slot + 4] = o4[1];
    *(float4*)&scrB[slot + 0] = o4[2];
    *(float4*)&scrB[slot + 4] = o4[3];
    __syncthreads();
    {
      int qq = tid >> 3;       // 0..31
      int d4 = tid & 7;        // 0..7
      int tqr = qq >> 2, j = qq & 3;
      const float* bank = (j < 2) ? scrA : scrB;
      int off = (j & 1) * 4;
      float4 of = {0.f, 0.f, 0.f, 0.f};
#pragma unroll
      for (int g = 0; g < 4; g++) {
        float4 part =
            *(const float4*)&bank[(g * 64 + tqr * 8 + d4) * 8 + off];
        of.x += part.x; of.y += part.y; of.z += part.z; of.w += part.w;
      }
      size_t idx = ((size_t)(qbase + qq) * HEADS + h) * NSPLIT + sp;
      *(float4*)&pacc[idx * 32 + d4 * 4] = of;
    }
    return;
  }
  // edge attention: 4 query edges/block; wave = head;
  // lane = (q 2b | nbr-slot 2b | dim-qtr 2b)
  int h = tid >> 6;
  int lane = tid & 63;
  int ql = lane >> 4, j4 = (lane >> 2) & 3, g = lane & 3;
  int qi = (bid - 1024) * 4 + ql;
  int dg = deg[qi];
  const float4* qp = (const float4*)(Qe + (size_t)qi * DIM + h * DH + g * 8);
  float4 q0 = qp[0], q1 = qp[1];
  float s = 0.f;
  float4 a0 = make_float4(0.f, 0.f, 0.f, 0.f);
  float4 a1 = make_float4(0.f, 0.f, 0.f, 0.f);
  for (int c0 = 0; c0 < dg; c0 += 4) {
    int j = c0 + j4;
    bool act = j < dg;
    int ei = act ? nbr[(size_t)qi * NBR_CAP + j] : 0;
    const float4* kp = (const float4*)(Ke + (size_t)ei * DIM + h * DH + g * 8);
    float4 k0 = kp[0], k1 = kp[1];
    float pd = q0.x * k0.x + q0.y * k0.y + q0.z * k0.z + q0.w * k0.w +
               q1.x * k1.x + q1.y * k1.y + q1.z * k1.z + q1.w * k1.w;
    pd += __shfl_xor(pd, 1, 64);
    pd += __shfl_xor(pd, 2, 64);  // full 32-dot in all 4 dim-qtr lanes
    float pr = act ? __expf(pd * SCALE) : 0.f;
    s += pr;
    const float4* vp = (const float4*)(Ve + (size_t)ei * DIM + h * DH + g * 8);
    float4 v0 = vp[0], v1 = vp[1];
    FMA4(a0, pr, v0);
    FMA4(a1, pr, v1);
  }
#pragma unroll
  for (int o = 4; o <= 8; o <<= 1) {
    s += __shfl_xor(s, o, 64);
    a0.x += __shfl_xor(a0.x, o, 64); a0.y += __shfl_xor(a0.y, o, 64);
    a0.z += __shfl_xor(a0.z, o, 64); a0.w += __shfl_xor(a0.w, o, 64);
    a1.x += __shfl_xor(a1.x, o, 64); a1.y += __shfl_xor(a1.y, o, 64);
    a1.z += __shfl_xor(a1.z, o, 64); a1.w += __shfl_xor(a1.w, o, 64);
  }
  if (j4 == 0) {
    float inv = 1.0f / s;
    float4* op = (float4*)(Oe + (size_t)qi * DIM + h * DH + g * 8);
    float4 r0 = {a0.x * inv, a0.y * inv, a0.z * inv, a0.w * inv};
    float4 r1 = {a1.x * inv, a1.y * inv, a1.z * inv, a1.w * inv};
    op[0] = r0;
    op[1] = r1;
  }
}

// ============ K3b: combine node-attn splits, normalize -> aon ===============
__global__ __launch_bounds__(256) void attn_reduce_kernel(
    const float* __restrict__ pacc, const float* __restrict__ ps,
    float* __restrict__ O) {
  int gid = blockIdx.x * 256 + threadIdx.x;
  int qh = gid >> 5, d = gid & 31;
  int q = qh >> 2, h = qh & 3;
  float ssum = 0.f, v = 0.f;
#pragma unroll
  for (int sp = 0; sp < NSPLIT; sp++) {
    size_t idx = (size_t)qh * NSPLIT + sp;
    ssum += ps[idx];
    v += pacc[idx * 32 + d];
  }
  O[(size_t)q * DIM + h * DH + d] = v / ssum;
}

// ============ K4: per 8 edge-rows: ue = aoe@wo_e + (aonS+aonD)@W_fused
//   + (bo_e + b_fused); h = gelu(ue @ w_c1 + b_c1); out = h @ w_c2 + b_c2 ===
__global__ __launch_bounds__(256) void tail_kernel(
    const float* __restrict__ aoe, const float* __restrict__ wo_e,
    const float* __restrict__ bo_e, const float* __restrict__ aon,
    const int* __restrict__ src, const int* __restrict__ dst,
    const float* __restrict__ wfu, const float* __restrict__ bfu,
    const float* __restrict__ w_c1, const float* __restrict__ b_c1,
    const float* __restrict__ w_c2, const float* __restrict__ b_c2,
    float* __restrict__ out) {
  // LDS: ue_s[8][132] @0 (4224) | As0[16][12] @4224 (768) |
  //      Bs[16][132] @4992 (8448) ; phase B: Bs2[16][264] @4224 (16896)
  //      phase C: wT[16][260] @4224 (16640, reuses Bs2 region)
  __shared__ __align__(16) char smem[21120];
  float (*ue_s)[132] = (float(*)[132])smem;
  float (*As0)[12] = (float(*)[12])(smem + 4224);
  float (*Bs)[132] = (float(*)[132])(smem + 4992);
  float (*Bs2)[264] = (float(*)[264])(smem + 4224);
  float* wT = (float*)(smem + 4224);  // [16 cols][260] (k stride 1)
  int tid = threadIdx.x;
  int bm = blockIdx.x * 8;
  int tr = tid >> 5;          // 1 row per thread
  int tn = (tid & 31) * 4;    // 4 cols (of 128)
  float4 acc = {0, 0, 0, 0};
  // ---- GEMM 1: aoe rows @ wo_e ----
  for (int k0 = 0; k0 < DIM; k0 += 16) {
    if (tid < 128) {
      int r = tid >> 4, kk = tid & 15;
      As0[kk][r] = aoe[(size_t)(bm + r) * DIM + k0 + kk];
    }
#pragma unroll
    for (int i = 0; i < 8; i++) {
      int id = i * 256 + tid;
      int kb = id >> 7, c = id & 127;
      Bs[kb][c] = wo_e[(size_t)(k0 + kb) * DIM + c];
    }
    __syncthreads();
#pragma unroll
    for (int kk = 0; kk < 16; kk++) {
      float a = As0[kk][tr];
      float4 b = *(const float4*)&Bs[kk][tn];
      FMA4(acc, a, b);
    }
    __syncthreads();
  }
  // ---- GEMM 2 (accumulate): (aon[src]+aon[dst]) rows @ W_fused ----
  for (int k0 = 0; k0 < DIM; k0 += 16) {
    if (tid < 128) {
      int r = tid >> 4, kk = tid & 15;
      int row = bm + r;
      int s0 = src[row], d0 = dst[row];
      As0[kk][r] = aon[(size_t)s0 * DIM + k0 + kk] +
                   aon[(size_t)d0 * DIM + k0 + kk];
    }
#pragma unroll
    for (int i = 0; i < 8; i++) {
      int id = i * 256 + tid;
      int kb = id >> 7, c = id & 127;
      Bs[kb][c] = wfu[(size_t)(k0 + kb) * DIM + c];
    }
    __syncthreads();
#pragma unroll
    for (int kk = 0; kk < 16; kk++) {
      float a = As0[kk][tr];
      float4 b = *(const float4*)&Bs[kk][tn];
      FMA4(acc, a, b);
    }
    __syncthreads();
  }
  // ---- ue = acc + bo_e + b_fused -> LDS ----
  {
    float4 be = *(const float4*)&bo_e[tn];
    float4 bf = *(const float4*)&bfu[tn];
    float4 r;
    r.x = acc.x + be.x + bf.x; r.y = acc.y + be.y + bf.y;
    r.z = acc.z + be.z + bf.z; r.w = acc.w + be.w + bf.w;
    *(float4*)&ue_s[tr][tn] = r;
  }
  __syncthreads();
  // ---- GEMM 3: h = gelu(ue @ w_c1 + b_c1), 8x256, h kept in registers ----
  int c4 = (tid & 31) * 4;  // cols c4 and c4+128
  float4 acc2[2] = {{0,0,0,0},{0,0,0,0}};
  for (int k0 = 0; k0 < DIM; k0 += 16) {
#pragma unroll
    for (int i = 0; i < 16; i++) {
      int id = i * 256 + tid;
      int kb = id >> 8, c = id & 255;
      Bs2[kb][c] = w_c1[(size_t)(k0 + kb) * 256 + c];
    }
    __syncthreads();
#pragma unroll
    for (int kk = 0; kk < 16; kk++) {
      float av = ue_s[tr][k0 + kk];
      float4 bva = *(const float4*)&Bs2[kk][c4];
      float4 bvb = *(const float4*)&Bs2[kk][c4 + 128];
      FMA4(acc2[0], av, bva);
      FMA4(acc2[1], av, bvb);
    }
    __syncthreads();
  }
  float hv[2][4];
  {
    float4 bc0 = *(const float4*)&b_c1[c4];
    float4 bc1 = *(const float4*)&b_c1[c4 + 128];
#pragma unroll
    for (int half = 0; half < 2; half++) {
      float4 bb = half ? bc1 : bc0;
      float4 av = acc2[half];
      float vv[4] = {av.x + bb.x, av.y + bb.y, av.z + bb.z, av.w + bb.w};
#pragma unroll
      for (int j = 0; j < 4; j++) {
        float v = vv[j];
        float u = 0.7978845608028654f * (v + 0.044715f * v * v * v);
        hv[half][j] = 0.5f * v * (1.0f + tanhf(u));
      }
    }
  }
  // ---- out = h @ w_c2 + b_c2 : stage w_c2 transposed, dot, butterfly ----
  __syncthreads();  // Bs2 dead -> wT
#pragma unroll
  for (int i = 0; i < 4; i++) {
    int id = i * 256 + tid;  // fl4 index into w_c2 [256][16]
    float4 w4 = ((const float4*)w_c2)[id];
    int k = id >> 2, cc = (id & 3) * 4;
    wT[(cc + 0) * 260 + k] = w4.x;
    wT[(cc + 1) * 260 + k] = w4.y;
    wT[(cc + 2) * 260 + k] = w4.z;
    wT[(cc + 3) * 260 + k] = w4.w;
  }
  __syncthreads();
  float oacc[NCLS];
#pragma unroll
  for (int c = 0; c < NCLS; c++) {
    float4 wa = *(const float4*)&wT[c * 260 + c4];
    float4 wb = *(const float4*)&wT[c * 260 + c4 + 128];
    float v = hv[0][0] * wa.x;
    v = fmaf(hv[0][1], wa.y, v);
    v = fmaf(hv[0][2], wa.z, v);
    v = fmaf(hv[0][3], wa.w, v);
    v = fmaf(hv[1][0], wb.x, v);
    v = fmaf(hv[1][1], wb.y, v);
    v = fmaf(hv[1][2], wb.z, v);
    v = fmaf(hv[1][3], wb.w, v);
    oacc[c] = v;
  }
  // butterfly over the row's 32 contiguous lanes (offsets <=16 stay in-row)
#pragma unroll
  for (int os = 1; os < 32; os <<= 1) {
#pragma unroll
    for (int c = 0; c < NCLS; c++) oacc[c] += __shfl_xor(oacc[c], os, 64);
  }
  if ((tid & 31) < NCLS) {
    int col = tid & 15;
    out[(size_t)(bm + tr) * NCLS + col] = oacc[col] + b_c2[col];
  }
}

extern "C" void kernel_launch(void* const* d_in, const int* in_sizes, int n_in,
                              void* d_out, int out_size, void* d_ws,
                              size_t ws_size, hipStream_t stream) {
  const float* nf = (const float*)d_in[0];
  const float* ef = (const float*)d_in[1];
  const int* ei = (const int*)d_in[2];
  const float* w_rn = (const float*)d_in[3];
  const float* b_rn = (const float*)d_in[4];
  const float* w_re = (const float*)d_in[5];
  const float* b_re = (const float*)d_in[6];
  const float* wq_n = (const float*)d_in[7];
  const float* bq_n = (const float*)d_in[8];
  const float* wk_n = (const float*)d_in[9];
  const float* bk_n = (const float*)d_in[10];
  const float* wv_n = (const float*)d_in[11];
  const float* bv_n = (const float*)d_in[12];
  const float* wo_n = (const float*)d_in[13];
  const float* bo_n = (const float*)d_in[14];
  const float* wq_e = (const float*)d_in[15];
  const float* bq_e = (const float*)d_in[16];
  const float* wk_e = (const float*)d_in[17];
  const float* bk_e = (const float*)d_in[18];
  const float* wv_e = (const float*)d_in[19];
  const float* bv_e = (const float*)d_in[20];
  const float* wo_e = (const float*)d_in[21];
  const float* bo_e = (const float*)d_in[22];
  const float* w_ne = (const float*)d_in[23];
  const float* b_ne = (const float*)d_in[24];
  const float* w_c1 = (const float*)d_in[25];
  const float* b_c1 = (const float*)d_in[26];
  const float* w_c2 = (const float*)d_in[27];
  const float* b_c2 = (const float*)d_in[28];

  const int* src = ei;
  const int* dst = ei + N_EDGES;

  float* ws = (float*)d_ws;
  size_t o = 0;
  float* ns = ws + o;   o += 2048;
  float* es = ws + o;   o += 4096;
  int* kidx = (int*)(ws + o); o += 2048;
  int* nkept = (int*)(ws + o); o += 64;
  int* nbr = (int*)(ws + o); o += (size_t)N_EDGES * NBR_CAP;
  int* degp = (int*)(ws + o); o += N_EDGES;
  float* wfu = ws + o;  o += DIM * DIM;
  float* bfu = ws + o;  o += DIM;
  float* qn = ws + o;   o += (size_t)N_NODES * DIM;
  float* kn = ws + o;   o += (size_t)N_NODES * DIM;
  float* vn = ws + o;   o += (size_t)N_NODES * DIM;
  float* qe = ws + o;   o += (size_t)N_EDGES * DIM;
  float* ke = ws + o;   o += (size_t)N_EDGES * DIM;
  float* ve = ws + o;   o += (size_t)N_EDGES * DIM;
  float* aon = ws + o;  o += (size_t)N_NODES * DIM;
  float* aoe = ws + o;  o += (size_t)N_EDGES * DIM;
  float* pacc = ws + o; o += (size_t)N_NODES * HEADS * NSPLIT * DH;
  float* ps = ws + o;   o += (size_t)N_NODES * HEADS * NSPLIT;

  // K1: scores + nbr lists + W_fused/b_fused (all independent)
  prep_kernel<<<dim3(2565), 256, 0, stream>>>(
      nf, ef, w_rn, b_rn, w_re, b_re, src, dst, wo_n, bo_n, w_ne, b_ne,
      ns, es, nbr, degp, wfu, bfu);
  // K2: topk + six QKV projections (gating fused into A-stage)
  topk_qkv_kernel<<<dim3(289), 256, 0, stream>>>(
      nf, ef, ns, es, wq_n, wk_n, wv_n, wq_e, wk_e, wv_e,
      bq_n, bk_n, bv_n, bq_e, bk_e, bv_e, qn, kn, vn, qe, ke, ve,
      kidx, nkept);
  // K3: node attention (two-GEMM, key-split x4, partials) + edge attention
  attn_kernel<<<dim3(2048), 256, 0, stream>>>(
      qn, kn, vn, kidx, nkept, pacc, ps, qe, ke, ve, nbr, degp, aoe);
  // K3b: combine splits -> aon (CP barrier is cheaper than device fences)
  attn_reduce_kernel<<<dim3(N_NODES * HEADS * DH / 256), 256, 0, stream>>>(
      pacc, ps, aon);
  // K4: ue -> gelu -> out (single fused tail, writes d_out)
  tail_kernel<<<dim3(N_EDGES / 8), 256, 0, stream>>>(
      aoe, wo_e, bo_e, aon, src, dst, wfu, bfu, w_c1, b_c1, w_c2, b_c2,
      (float*)d_out);
}

// Round 17
// 101.053 us; speedup vs baseline: 1.8490x; 1.2729x over previous
//
#include <hip/hip_runtime.h>
#include <math.h>

#define N_NODES 2048
#define N_EDGES 4096
#define DIM 128
#define HEADS 4
#define DH 32
#define NCLS 16
#define TOPK 1024
#define NBR_CAP 64
#define NSPLIT 4
#define QB 32  // queries per attn_node unit
#define SCALE 0.17677669529663687f  // 1/sqrt(32)

#define FMA4(ACC, AS, BV)                                       \
  ACC.x = fmaf(AS, BV.x, ACC.x); ACC.y = fmaf(AS, BV.y, ACC.y); \
  ACC.z = fmaf(AS, BV.z, ACC.z); ACC.w = fmaf(AS, BV.w, ACC.w)

__device__ __forceinline__ float wave_reduce_sum(float v) {
#pragma unroll
  for (int o = 32; o > 0; o >>= 1) v += __shfl_xor(v, o, 64);
  return v;
}

// ============ K1: scores (0..1535) + nbr lists (1536..2559, 4 q/block) +
//              W_fused (2560..2563) + b_fused (2564) ========================
__global__ __launch_bounds__(256) void prep_kernel(
    const float* __restrict__ nf, const float* __restrict__ ef,
    const float* __restrict__ w_rn, const float* __restrict__ b_rn,
    const float* __restrict__ w_re, const float* __restrict__ b_re,
    const int* __restrict__ src, const int* __restrict__ dst,
    const float* __restrict__ wo_n, const float* __restrict__ bo_n,
    const float* __restrict__ w_ne, const float* __restrict__ b_ne,
    float* __restrict__ ns, float* __restrict__ es, int* __restrict__ nbr,
    int* __restrict__ deg, float* __restrict__ wfu, float* __restrict__ bfu) {
  int tid = threadIdx.x;
  int bid = blockIdx.x;
  if (bid < 1536) {  // router scores: 4 rows/block, 1 per wave
    int wid = tid >> 6, lane = tid & 63;
    int row = bid * 4 + wid;
    const float* feat;
    const float* w;
    float b;
    float* scp;
    if (row < N_NODES) {
      feat = nf + (size_t)row * DIM;
      w = w_rn; b = b_rn[0];
      scp = ns + row;
    } else {
      int r = row - N_NODES;
      feat = ef + (size_t)r * DIM;
      w = w_re; b = b_re[0];
      scp = es + r;
    }
    float d = feat[lane] * w[lane] + feat[lane + 64] * w[lane + 64];
    d = wave_reduce_sum(d);
    if (lane == 0) *scp = 1.0f / (1.0f + __expf(-(d + b)));
    return;
  }
  if (bid < 2560) {  // line-graph neighbor lists: 4 query edges/block
    __shared__ int sL[N_EDGES];
    __shared__ int dL[N_EDGES];
    __shared__ int cnt[4];
    int bq = bid - 1536;
#pragma unroll
    for (int i = 0; i < 16; i++) {
      int j = i * 256 + tid;
      sL[j] = src[j];
      dL[j] = dst[j];
    }
    if (tid < 4) cnt[tid] = 0;
    __syncthreads();
    int w = tid >> 6, lane = tid & 63;
    int qi = bq * 4 + w;
    int sq = sL[qi], dq = dL[qi];
    for (int j = lane; j < N_EDGES; j += 64) {
      int sj = sL[j], dj = dL[j];
      if (sj == sq || sj == dq || dj == sq || dj == dq) {
        int pos = atomicAdd(&cnt[w], 1);
        if (pos < NBR_CAP) nbr[(size_t)qi * NBR_CAP + pos] = j;
      }
    }
    __syncthreads();
    if (tid < 4) deg[bq * 4 + tid] = min(cnt[tid], NBR_CAP);
    return;
  }
  if (bid < 2564) {  // W_fused = wo_n @ w_ne, 64x64 tiles
    __shared__ float As[16][68];
    __shared__ float Bs[16][68];
    int idx = bid - 2560;
    int bm = (idx >> 1) * 64, bn = (idx & 1) * 64;
    int tm = (tid >> 4) * 4, tn = (tid & 15) * 4;
    float4 acc[4] = {{0,0,0,0},{0,0,0,0},{0,0,0,0},{0,0,0,0}};
    for (int k0 = 0; k0 < DIM; k0 += 16) {
#pragma unroll
      for (int i = 0; i < 4; i++) {
        int e = i * 256 + tid;
        int r = e >> 4, kk = e & 15;
        As[kk][r] = wo_n[(size_t)(bm + r) * DIM + k0 + kk];
        int kb = e >> 6, c = e & 63;
        Bs[kb][c] = w_ne[(size_t)(k0 + kb) * DIM + bn + c];
      }
      __syncthreads();
#pragma unroll
      for (int kk = 0; kk < 16; kk++) {
        float4 a = *(const float4*)&As[kk][tm];
        float4 b = *(const float4*)&Bs[kk][tn];
        FMA4(acc[0], a.x, b); FMA4(acc[1], a.y, b);
        FMA4(acc[2], a.z, b); FMA4(acc[3], a.w, b);
      }
      __syncthreads();
    }
#pragma unroll
    for (int i = 0; i < 4; i++)
      *(float4*)&wfu[(size_t)(bm + tm + i) * DIM + bn + tn] = acc[i];
    return;
  }
  // b_fused = 2*(bo_n @ w_ne) + b_ne
  if (tid < DIM) {
    float a = 0.f;
    for (int k = 0; k < DIM; k++)
      a = fmaf(bo_n[k], w_ne[(size_t)k * DIM + tid], a);
    bfu[tid] = 2.f * a + b_ne[tid];
  }
}

// ============ 128x64 GEMM body, bank-conflict-free A reads (g4 / g4+64) ====
typedef float As128T[16][136];
typedef float Bs68T[16][68];
__device__ __forceinline__ void gemm_body128(
    As128T& As, Bs68T& Bs, const float* __restrict__ A,
    const float* __restrict__ B, const float* gs, int bm, int bn, int K,
    int N, float4 (&acc)[8], int tid) {
  int g4 = (tid >> 4) * 4, tn = (tid & 15) * 4;
  for (int k0 = 0; k0 < K; k0 += 16) {
#pragma unroll
    for (int i = 0; i < 8; i++) {
      int e = i * 256 + tid;
      int r = e >> 4, kk = e & 15;
      float a = A[(size_t)(bm + r) * K + k0 + kk];
      As[kk][r] = gs ? a * gs[r] : a;
    }
#pragma unroll
    for (int i = 0; i < 4; i++) {
      int e = i * 256 + tid;
      int kb = e >> 6, c = e & 63;
      Bs[kb][c] = B[(size_t)(k0 + kb) * N + bn + c];
    }
    __syncthreads();
#pragma unroll
    for (int kk = 0; kk < 16; kk++) {
      float4 a0 = *(const float4*)&As[kk][g4];
      float4 a1 = *(const float4*)&As[kk][g4 + 64];
      float4 b = *(const float4*)&Bs[kk][tn];
      FMA4(acc[0], a0.x, b); FMA4(acc[1], a0.y, b);
      FMA4(acc[2], a0.z, b); FMA4(acc[3], a0.w, b);
      FMA4(acc[4], a1.x, b); FMA4(acc[5], a1.y, b);
      FMA4(acc[6], a1.z, b); FMA4(acc[7], a1.w, b);
    }
    __syncthreads();
  }
}

// ============ K2: topk (block 0) + six QKV GEMM tiles (1..288) ==============
__global__ __launch_bounds__(256) void topk_qkv_kernel(
    const float* __restrict__ nf, const float* __restrict__ ef,
    const float* __restrict__ ns, const float* __restrict__ es,
    const float* __restrict__ wq_n, const float* __restrict__ wk_n,
    const float* __restrict__ wv_n, const float* __restrict__ wq_e,
    const float* __restrict__ wk_e, const float* __restrict__ wv_e,
    const float* __restrict__ bq_n, const float* __restrict__ bk_n,
    const float* __restrict__ bv_n, const float* __restrict__ bq_e,
    const float* __restrict__ bk_e, const float* __restrict__ bv_e,
    float* __restrict__ qn, float* __restrict__ kn, float* __restrict__ vn,
    float* __restrict__ qe, float* __restrict__ ke, float* __restrict__ ve,
    int* __restrict__ kidx, int* __restrict__ nkept) {
  __shared__ float As[16][136];
  __shared__ float Bs[16][68];
  __shared__ float ss[128];
  __shared__ unsigned sh_lo;
  __shared__ int wcnt;
  int tid = threadIdx.x;
  if (blockIdx.x == 0) {
    // kth largest = max{v : count(s>=v) >= k}; single-wave binary search on
    // float bits (sigmoid in (0,1) -> bit order == value order; 64-bit
    // midpoint: u32 overflow hung round 1).
    if (tid == 0) wcnt = 0;
    if (tid < 64) {
      unsigned bv[32];
#pragma unroll
      for (int i = 0; i < 32; i++) bv[i] = __float_as_uint(ns[tid * 32 + i]);
      unsigned lo = 0u, hi = 0x3F800000u;  // scores < 1.0f
      while (lo < hi) {
        unsigned mid = (unsigned)(((unsigned long long)lo + hi + 1ull) >> 1);
        int c = 0;
#pragma unroll
        for (int i = 0; i < 32; i++) c += (bv[i] >= mid);
#pragma unroll
        for (int o = 1; o < 64; o <<= 1) c += __shfl_xor(c, o, 64);
        if (c >= TOPK) lo = mid; else hi = mid - 1;
      }
      if (tid == 0) sh_lo = lo;
    }
    __syncthreads();
    unsigned lo = sh_lo;
#pragma unroll
    for (int i = 0; i < 8; i++) {
      int idx = tid * 8 + i;
      if (__float_as_uint(ns[idx]) >= lo) kidx[atomicAdd(&wcnt, 1)] = idx;
    }
    __syncthreads();
    if (tid == 0) nkept[0] = wcnt;
    return;
  }
  int bx = blockIdx.x - 1;  // 0..287
  bool edge = bx >= 96;
  int mat, bm, bn;
  const float* A;
  const float* sc;
  if (!edge) {
    mat = bx / 32;
    int rem = bx % 32;
    bm = (rem >> 1) * 128;
    bn = (rem & 1) * 64;
    A = nf; sc = ns;
  } else {
    int be = bx - 96;
    mat = be / 64;
    int rem = be % 64;
    bm = (rem >> 1) * 128;
    bn = (rem & 1) * 64;
    A = ef; sc = es;
  }
  const float* W;
  const float* bias;
  float* C;
  if (!edge) {
    if (mat == 0) { W = wq_n; bias = bq_n; C = qn; }
    else if (mat == 1) { W = wk_n; bias = bk_n; C = kn; }
    else { W = wv_n; bias = bv_n; C = vn; }
  } else {
    if (mat == 0) { W = wq_e; bias = bq_e; C = qe; }
    else if (mat == 1) { W = wk_e; bias = bk_e; C = ke; }
    else { W = wv_e; bias = bv_e; C = ve; }
  }
  if (tid < 128) ss[tid] = sc[bm + tid];
  __syncthreads();
  float4 acc[8] = {{0,0,0,0},{0,0,0,0},{0,0,0,0},{0,0,0,0},
                   {0,0,0,0},{0,0,0,0},{0,0,0,0},{0,0,0,0}};
  gemm_body128(As, Bs, A, W, ss, bm, bn, DIM, DIM, acc, tid);
  int g4 = (tid >> 4) * 4, tn = (tid & 15) * 4;
  float4 b4 = *(const float4*)&bias[bn + tn];
#pragma unroll
  for (int i = 0; i < 4; i++) {
    float4 r;
    r.x = acc[i].x + b4.x; r.y = acc[i].y + b4.y;
    r.z = acc[i].z + b4.z; r.w = acc[i].w + b4.w;
    *(float4*)&C[(size_t)(bm + g4 + i) * DIM + bn + tn] = r;
  }
#pragma unroll
  for (int i = 0; i < 4; i++) {
    float4 r;
    r.x = acc[4 + i].x + b4.x; r.y = acc[4 + i].y + b4.y;
    r.z = acc[4 + i].z + b4.z; r.w = acc[4 + i].w + b4.w;
    *(float4*)&C[(size_t)(bm + 64 + g4 + i) * DIM + bn + tn] = r;
  }
}

// ============ K3: node attn as two GEMMs (blocks 0..1023, key-split x4,
//              fence-free partials) + edge attn (blocks 1024..2047) =========
__global__ __launch_bounds__(256) void attn_kernel(
    const float* __restrict__ Q, const float* __restrict__ K,
    const float* __restrict__ V, const int* __restrict__ kidx,
    const int* __restrict__ nkeptp, float* __restrict__ pacc,
    float* __restrict__ ps,
    const float* __restrict__ Qe, const float* __restrict__ Ke,
    const float* __restrict__ Ve, const int* __restrict__ nbr,
    const int* __restrict__ deg, float* __restrict__ Oe) {
  __shared__ float Qs[32][36];  // [d][q] transposed
  __shared__ float Ks[64][36];  // [k][d]
  __shared__ float Vs[64][36];  // [k][d]
  __shared__ float Ps[32][68];  // [q][k]
  int tid = threadIdx.x;
  int bid = blockIdx.x;
  if (bid < 1024) {
    int bxa = bid & 63;
    int h = (bid >> 6) & 3;
    int sp = bid >> 8;
    int qbase = bxa * QB;
    int nkept = nkeptp[0];
    int spl = (nkept + NSPLIT - 1) / NSPLIT;
    int start = sp * spl;
    int end = min(start + spl, nkept);

    // stage Q transposed: thread (q8 = tid>>3, d8 = tid&7)
    {
      int q8 = tid >> 3, d8 = tid & 7;
      const float4* qp =
          (const float4*)(Q + (size_t)(qbase + q8) * DIM + h * DH) + d8;
      float4 qv = *qp;
      Qs[d8 * 4 + 0][q8] = qv.x;
      Qs[d8 * 4 + 1][q8] = qv.y;
      Qs[d8 * 4 + 2][q8] = qv.z;
      Qs[d8 * 4 + 3][q8] = qv.w;
    }

    int tq = tid >> 5;          // 0..7 (GEMM1 q-group)
    int tk = tid & 31;          // GEMM1: keys tk, tk+32
    int kg = tid >> 6;          // GEMM2: key quarter (16 keys)
    int tq2 = (tid >> 3) & 7;   // GEMM2: q-group
    int td4 = tid & 7;          // GEMM2: d-quad
    float4 o4[4] = {{0,0,0,0},{0,0,0,0},{0,0,0,0},{0,0,0,0}};
    float sump[4] = {0.f, 0.f, 0.f, 0.f};

    for (int t0 = start; t0 < end; t0 += 64) {
#pragma unroll
      for (int i = 0; i < 2; i++) {
        int id = i * 256 + tid;
        int r = id >> 3, c4 = id & 7;
        int row = t0 + r;
        int ki = (row < end) ? kidx[row] : kidx[0];
        const float4* kp = (const float4*)(K + (size_t)ki * DIM + h * DH) + c4;
        const float4* vp = (const float4*)(V + (size_t)ki * DIM + h * DH) + c4;
        *(float4*)&Ks[r][c4 * 4] = *kp;
        *(float4*)&Vs[r][c4 * 4] = *vp;
      }
      __syncthreads();
      // GEMM1: s[q 4][k 2] over 32 dims
      float4 s0v = {0.f, 0.f, 0.f, 0.f};  // k = tk
      float4 s1v = {0.f, 0.f, 0.f, 0.f};  // k = tk+32
#pragma unroll
      for (int kk4 = 0; kk4 < 8; kk4++) {
        int kk = kk4 * 4;
        float4 ka = *(const float4*)&Ks[tk][kk];
        float4 kb = *(const float4*)&Ks[tk + 32][kk];
        float4 qa = *(const float4*)&Qs[kk + 0][tq * 4];
        float4 qb = *(const float4*)&Qs[kk + 1][tq * 4];
        float4 qc = *(const float4*)&Qs[kk + 2][tq * 4];
        float4 qd = *(const float4*)&Qs[kk + 3][tq * 4];
        FMA4(s0v, ka.x, qa); FMA4(s0v, ka.y, qb);
        FMA4(s0v, ka.z, qc); FMA4(s0v, ka.w, qd);
        FMA4(s1v, kb.x, qa); FMA4(s1v, kb.y, qb);
        FMA4(s1v, kb.z, qc); FMA4(s1v, kb.w, qd);
      }
      // batched exp (scores tiny -> no running max), P write, sum partials
      bool va = (t0 + tk) < end;
      bool vb = (t0 + tk + 32) < end;
      float p00 = va ? __expf(s0v.x * SCALE) : 0.f;
      float p01 = va ? __expf(s0v.y * SCALE) : 0.f;
      float p02 = va ? __expf(s0v.z * SCALE) : 0.f;
      float p03 = va ? __expf(s0v.w * SCALE) : 0.f;
      float p10 = vb ? __expf(s1v.x * SCALE) : 0.f;
      float p11 = vb ? __expf(s1v.y * SCALE) : 0.f;
      float p12 = vb ? __expf(s1v.z * SCALE) : 0.f;
      float p13 = vb ? __expf(s1v.w * SCALE) : 0.f;
      Ps[tq * 4 + 0][tk] = p00;      Ps[tq * 4 + 1][tk] = p01;
      Ps[tq * 4 + 2][tk] = p02;      Ps[tq * 4 + 3][tk] = p03;
      Ps[tq * 4 + 0][tk + 32] = p10; Ps[tq * 4 + 1][tk + 32] = p11;
      Ps[tq * 4 + 2][tk + 32] = p12; Ps[tq * 4 + 3][tk + 32] = p13;
      sump[0] += p00 + p10;
      sump[1] += p01 + p11;
      sump[2] += p02 + p12;
      sump[3] += p03 + p13;
      __syncthreads();
      // GEMM2: o[q 4][d 4] += P[q][k] * V[k][d] over this thread's 16 keys
#pragma unroll
      for (int k4 = 0; k4 < 4; k4++) {
        int kb = kg * 16 + k4 * 4;
        float4 p0 = *(const float4*)&Ps[tq2 * 4 + 0][kb];
        float4 p1 = *(const float4*)&Ps[tq2 * 4 + 1][kb];
        float4 p2 = *(const float4*)&Ps[tq2 * 4 + 2][kb];
        float4 p3 = *(const float4*)&Ps[tq2 * 4 + 3][kb];
        float4 v0 = *(const float4*)&Vs[kb + 0][td4 * 4];
        float4 v1 = *(const float4*)&Vs[kb + 1][td4 * 4];
        float4 v2 = *(const float4*)&Vs[kb + 2][td4 * 4];
        float4 v3 = *(const float4*)&Vs[kb + 3][td4 * 4];
        FMA4(o4[0], p0.x, v0); FMA4(o4[0], p0.y, v1);
        FMA4(o4[0], p0.z, v2); FMA4(o4[0], p0.w, v3);
        FMA4(o4[1], p1.x, v0); FMA4(o4[1], p1.y, v1);
        FMA4(o4[1], p1.z, v2); FMA4(o4[1], p1.w, v3);
        FMA4(o4[2], p2.x, v0); FMA4(o4[2], p2.y, v1);
        FMA4(o4[2], p2.z, v2); FMA4(o4[2], p2.w, v3);
        FMA4(o4[3], p3.x, v0); FMA4(o4[3], p3.y, v1);
        FMA4(o4[3], p3.z, v2); FMA4(o4[3], p3.w, v3);
      }
      __syncthreads();
    }
    // reduce sump over the 32 tk lanes (half-wave, matches tq grouping)
#pragma unroll
    for (int os = 1; os < 32; os <<= 1) {
#pragma unroll
      for (int j = 0; j < 4; j++) sump[j] += __shfl_xor(sump[j], os, 64);
    }
    if (tk == 0) {
#pragma unroll
      for (int j = 0; j < 4; j++) {
        int q = qbase + tq * 4 + j;
        size_t idx = ((size_t)q * HEADS + h) * NSPLIT + sp;
        ps[idx] = sump[j];
      }
    }
    // reduce o4 across the 4 kg groups via scratch carved from Ks/Vs
    float* scrA = &Ks[0][0];  // j = 0,1
    float* scrB = &Vs[0][0];  // j = 2,3
    int slot = (kg * 64 + tq2 * 8 + td4) * 8;
    *(float4*)&scrA[slot + 0] = o4[0];
    *(float4*)&scrA[slot + 4] = o4[1];
    *(float4*)&scrB[slot + 0] = o4[2];
    *(float4*)&scrB[slot + 4] = o4[3];
    __syncthreads();
    {
      int qq = tid >> 3;       // 0..31
      int d4 = tid & 7;        // 0..7
      int tqr = qq >> 2, j = qq & 3;
      const float* bank = (j < 2) ? scrA : scrB;
      int off = (j & 1) * 4;
      float4 of = {0.f, 0.f, 0.f, 0.f};
#pragma unroll
      for (int g = 0; g < 4; g++) {
        float4 part =
            *(const float4*)&bank[(g * 64 + tqr * 8 + d4) * 8 + off];
        of.x += part.x; of.y += part.y; of.z += part.z; of.w += part.w;
      }
      size_t idx = ((size_t)(qbase + qq) * HEADS + h) * NSPLIT + sp;
      *(float4*)&pacc[idx * 32 + d4 * 4] = of;
    }
    return;
  }
  // edge attention: 4 query edges/block; wave = head;
  // lane = (q 2b | nbr-slot 2b | dim-qtr 2b)
  int h = tid >> 6;
  int lane = tid & 63;
  int ql = lane >> 4, j4 = (lane >> 2) & 3, g = lane & 3;
  int qi = (bid - 1024) * 4 + ql;
  int dg = deg[qi];
  const float4* qp = (const float4*)(Qe + (size_t)qi * DIM + h * DH + g * 8);
  float4 q0 = qp[0], q1 = qp[1];
  float s = 0.f;
  float4 a0 = make_float4(0.f, 0.f, 0.f, 0.f);
  float4 a1 = make_float4(0.f, 0.f, 0.f, 0.f);
  for (int c0 = 0; c0 < dg; c0 += 4) {
    int j = c0 + j4;
    bool act = j < dg;
    int ei = act ? nbr[(size_t)qi * NBR_CAP + j] : 0;
    const float4* kp = (const float4*)(Ke + (size_t)ei * DIM + h * DH + g * 8);
    float4 k0 = kp[0], k1 = kp[1];
    float pd = q0.x * k0.x + q0.y * k0.y + q0.z * k0.z + q0.w * k0.w +
               q1.x * k1.x + q1.y * k1.y + q1.z * k1.z + q1.w * k1.w;
    pd += __shfl_xor(pd, 1, 64);
    pd += __shfl_xor(pd, 2, 64);  // full 32-dot in all 4 dim-qtr lanes
    float pr = act ? __expf(pd * SCALE) : 0.f;
    s += pr;
    const float4* vp = (const float4*)(Ve + (size_t)ei * DIM + h * DH + g * 8);
    float4 v0 = vp[0], v1 = vp[1];
    FMA4(a0, pr, v0);
    FMA4(a1, pr, v1);
  }
#pragma unroll
  for (int o = 4; o <= 8; o <<= 1) {
    s += __shfl_xor(s, o, 64);
    a0.x += __shfl_xor(a0.x, o, 64); a0.y += __shfl_xor(a0.y, o, 64);
    a0.z += __shfl_xor(a0.z, o, 64); a0.w += __shfl_xor(a0.w, o, 64);
    a1.x += __shfl_xor(a1.x, o, 64); a1.y += __shfl_xor(a1.y, o, 64);
    a1.z += __shfl_xor(a1.z, o, 64); a1.w += __shfl_xor(a1.w, o, 64);
  }
  if (j4 == 0) {
    float inv = 1.0f / s;
    float4* op = (float4*)(Oe + (size_t)qi * DIM + h * DH + g * 8);
    float4 r0 = {a0.x * inv, a0.y * inv, a0.z * inv, a0.w * inv};
    float4 r1 = {a1.x * inv, a1.y * inv, a1.z * inv, a1.w * inv};
    op[0] = r0;
    op[1] = r1;
  }
}

// ============ K3b: combine node-attn splits, normalize -> aon ===============
__global__ __launch_bounds__(256) void attn_reduce_kernel(
    const float* __restrict__ pacc, const float* __restrict__ ps,
    float* __restrict__ O) {
  int gid = blockIdx.x * 256 + threadIdx.x;
  int qh = gid >> 5, d = gid & 31;
  int q = qh >> 2, h = qh & 3;
  float ssum = 0.f, v = 0.f;
#pragma unroll
  for (int sp = 0; sp < NSPLIT; sp++) {
    size_t idx = (size_t)qh * NSPLIT + sp;
    ssum += ps[idx];
    v += pacc[idx * 32 + d];
  }
  O[(size_t)q * DIM + h * DH + d] = v / ssum;
}

// ============ K4: per 8 edge-rows: ue = aoe@wo_e + (aonS+aonD)@W_fused
//   + (bo_e + b_fused); h = gelu(ue @ w_c1 + b_c1) -> hb ====================
// GEMM1+GEMM2 merged into ONE k-loop (stage both A rows and both B tiles
// together): 16 -> 8 staged iterations, 32 -> 16 syncs, 2 indep FMA chains.
__global__ __launch_bounds__(256) void tail_kernel(
    const float* __restrict__ aoe, const float* __restrict__ wo_e,
    const float* __restrict__ bo_e, const float* __restrict__ aon,
    const int* __restrict__ src, const int* __restrict__ dst,
    const float* __restrict__ wfu, const float* __restrict__ bfu,
    const float* __restrict__ w_c1, const float* __restrict__ b_c1,
    float* __restrict__ hb) {
  // LDS: ue_s[8][132] @0 (4224) | As0[16][12] @4224 | As1[16][12] @4992 |
  //      Bs1[16][132] @5760 (8448) | Bsw[16][132] @14208 (8448) -> 22656
  //      phase B: Bs2[16][264] @4224 (16896) -> 21120 (fits)
  __shared__ __align__(16) char smem[22656];
  float (*ue_s)[132] = (float(*)[132])smem;
  float (*As0)[12] = (float(*)[12])(smem + 4224);
  float (*As1)[12] = (float(*)[12])(smem + 4992);
  float (*Bs1)[132] = (float(*)[132])(smem + 5760);
  float (*Bsw)[132] = (float(*)[132])(smem + 14208);
  float (*Bs2)[264] = (float(*)[264])(smem + 4224);
  int tid = threadIdx.x;
  int bm = blockIdx.x * 8;
  int tr = tid >> 5;          // 1 row per thread
  int tn = (tid & 31) * 4;    // 4 cols (of 128)
  float4 acc = {0, 0, 0, 0};
  // ---- merged GEMM 1+2: acc = aoe@wo_e + (aonS+aonD)@W_fused ----
  for (int k0 = 0; k0 < DIM; k0 += 16) {
    if (tid < 128) {
      int r = tid >> 4, kk = tid & 15;
      As0[kk][r] = aoe[(size_t)(bm + r) * DIM + k0 + kk];
    } else {
      int t2 = tid - 128;
      int r = t2 >> 4, kk = t2 & 15;
      int row = bm + r;
      int s0 = src[row], d0 = dst[row];
      As1[kk][r] = aon[(size_t)s0 * DIM + k0 + kk] +
                   aon[(size_t)d0 * DIM + k0 + kk];
    }
#pragma unroll
    for (int i = 0; i < 8; i++) {
      int id = i * 256 + tid;
      int kb = id >> 7, c = id & 127;
      Bs1[kb][c] = wo_e[(size_t)(k0 + kb) * DIM + c];
      Bsw[kb][c] = wfu[(size_t)(k0 + kb) * DIM + c];
    }
    __syncthreads();
#pragma unroll
    for (int kk = 0; kk < 16; kk++) {
      float a0 = As0[kk][tr];
      float a1 = As1[kk][tr];
      float4 b0 = *(const float4*)&Bs1[kk][tn];
      float4 bw = *(const float4*)&Bsw[kk][tn];
      FMA4(acc, a0, b0);
      FMA4(acc, a1, bw);
    }
    __syncthreads();
  }
  // ---- ue = acc + bo_e + b_fused -> LDS ----
  {
    float4 be = *(const float4*)&bo_e[tn];
    float4 bf = *(const float4*)&bfu[tn];
    float4 r;
    r.x = acc.x + be.x + bf.x; r.y = acc.y + be.y + bf.y;
    r.z = acc.z + be.z + bf.z; r.w = acc.w + be.w + bf.w;
    *(float4*)&ue_s[tr][tn] = r;
  }
  __syncthreads();
  // ---- GEMM 3: h = gelu(ue @ w_c1 + b_c1), 8x256 -> hb ----
  int c4 = (tid & 31) * 4;  // cols c4 and c4+128
  float4 acc2[2] = {{0,0,0,0},{0,0,0,0}};
  for (int k0 = 0; k0 < DIM; k0 += 16) {
#pragma unroll
    for (int i = 0; i < 16; i++) {
      int id = i * 256 + tid;
      int kb = id >> 8, c = id & 255;
      Bs2[kb][c] = w_c1[(size_t)(k0 + kb) * 256 + c];
    }
    __syncthreads();
#pragma unroll
    for (int kk = 0; kk < 16; kk++) {
      float av = ue_s[tr][k0 + kk];
      float4 bva = *(const float4*)&Bs2[kk][c4];
      float4 bvb = *(const float4*)&Bs2[kk][c4 + 128];
      FMA4(acc2[0], av, bva);
      FMA4(acc2[1], av, bvb);
    }
    __syncthreads();
  }
  float4 bc0 = *(const float4*)&b_c1[c4];
  float4 bc1 = *(const float4*)&b_c1[c4 + 128];
#pragma unroll
  for (int half = 0; half < 2; half++) {
    float4 bb = half ? bc1 : bc0;
    float4 av = acc2[half];
    float vv[4] = {av.x + bb.x, av.y + bb.y, av.z + bb.z, av.w + bb.w};
#pragma unroll
    for (int j = 0; j < 4; j++) {
      float v = vv[j];
      float u = 0.7978845608028654f * (v + 0.044715f * v * v * v);
      vv[j] = 0.5f * v * (1.0f + tanhf(u));
    }
    float4 r = {vv[0], vv[1], vv[2], vv[3]};
    *(float4*)&hb[(size_t)(bm + tr) * 256 + c4 + half * 128] = r;
  }
}

// ============ K5: out = h @ w_c2 + b_c2 (8 rows/block, split-K x2) ==========
__global__ __launch_bounds__(256) void gemm_out_kernel(
    const float* __restrict__ Hm, const float* __restrict__ B,
    const float* __restrict__ bias, float* __restrict__ C) {
  __shared__ float Bs[256 * 16];
  __shared__ float red[256];
  int tid = threadIdx.x;
#pragma unroll
  for (int i = 0; i < 16; i++) Bs[i * 256 + tid] = B[i * 256 + tid];
  __syncthreads();
  int row = blockIdx.x * 8 + ((tid >> 4) & 7);
  int col = tid & 15;
  int half = tid >> 7;  // split K two ways
  const float* hp = Hm + (size_t)row * 256 + half * 128;
  float sacc = half ? 0.f : bias[col];
#pragma unroll 8
  for (int k = 0; k < 128; k++)
    sacc = fmaf(hp[k], Bs[(half * 128 + k) * 16 + col], sacc);
  red[tid] = sacc;
  __syncthreads();
  if (tid < 128)
    C[(size_t)row * NCLS + col] = red[tid] + red[tid + 128];
}

extern "C" void kernel_launch(void* const* d_in, const int* in_sizes, int n_in,
                              void* d_out, int out_size, void* d_ws,
                              size_t ws_size, hipStream_t stream) {
  const float* nf = (const float*)d_in[0];
  const float* ef = (const float*)d_in[1];
  const int* ei = (const int*)d_in[2];
  const float* w_rn = (const float*)d_in[3];
  const float* b_rn = (const float*)d_in[4];
  const float* w_re = (const float*)d_in[5];
  const float* b_re = (const float*)d_in[6];
  const float* wq_n = (const float*)d_in[7];
  const float* bq_n = (const float*)d_in[8];
  const float* wk_n = (const float*)d_in[9];
  const float* bk_n = (const float*)d_in[10];
  const float* wv_n = (const float*)d_in[11];
  const float* bv_n = (const float*)d_in[12];
  const float* wo_n = (const float*)d_in[13];
  const float* bo_n = (const float*)d_in[14];
  const float* wq_e = (const float*)d_in[15];
  const float* bq_e = (const float*)d_in[16];
  const float* wk_e = (const float*)d_in[17];
  const float* bk_e = (const float*)d_in[18];
  const float* wv_e = (const float*)d_in[19];
  const float* bv_e = (const float*)d_in[20];
  const float* wo_e = (const float*)d_in[21];
  const float* bo_e = (const float*)d_in[22];
  const float* w_ne = (const float*)d_in[23];
  const float* b_ne = (const float*)d_in[24];
  const float* w_c1 = (const float*)d_in[25];
  const float* b_c1 = (const float*)d_in[26];
  const float* w_c2 = (const float*)d_in[27];
  const float* b_c2 = (const float*)d_in[28];

  const int* src = ei;
  const int* dst = ei + N_EDGES;

  float* ws = (float*)d_ws;
  size_t o = 0;
  float* ns = ws + o;   o += 2048;
  float* es = ws + o;   o += 4096;
  int* kidx = (int*)(ws + o); o += 2048;
  int* nkept = (int*)(ws + o); o += 64;
  int* nbr = (int*)(ws + o); o += (size_t)N_EDGES * NBR_CAP;
  int* degp = (int*)(ws + o); o += N_EDGES;
  float* wfu = ws + o;  o += DIM * DIM;
  float* bfu = ws + o;  o += DIM;
  float* qn = ws + o;   o += (size_t)N_NODES * DIM;
  float* kn = ws + o;   o += (size_t)N_NODES * DIM;
  float* vn = ws + o;   o += (size_t)N_NODES * DIM;
  float* qe = ws + o;   o += (size_t)N_EDGES * DIM;
  float* ke = ws + o;   o += (size_t)N_EDGES * DIM;
  float* ve = ws + o;   o += (size_t)N_EDGES * DIM;
  float* aon = ws + o;  o += (size_t)N_NODES * DIM;
  float* aoe = ws + o;  o += (size_t)N_EDGES * DIM;
  float* hb = ws + o;   o += (size_t)N_EDGES * 2 * DIM;
  float* ps = ws + o;   o += (size_t)N_NODES * HEADS * NSPLIT;
  float* pacc = hb;  // alias: pacc lifetime (K3-K3b) ends before hb (K4-K5)

  // K1: scores + nbr lists + W_fused/b_fused (all independent)
  prep_kernel<<<dim3(2565), 256, 0, stream>>>(
      nf, ef, w_rn, b_rn, w_re, b_re, src, dst, wo_n, bo_n, w_ne, b_ne,
      ns, es, nbr, degp, wfu, bfu);
  // K2: topk + six QKV projections (gating fused into A-stage)
  topk_qkv_kernel<<<dim3(289), 256, 0, stream>>>(
      nf, ef, ns, es, wq_n, wk_n, wv_n, wq_e, wk_e, wv_e,
      bq_n, bk_n, bv_n, bq_e, bk_e, bv_e, qn, kn, vn, qe, ke, ve,
      kidx, nkept);
  // K3: node attention (two-GEMM, key-split x4, partials) + edge attention
  attn_kernel<<<dim3(2048), 256, 0, stream>>>(
      qn, kn, vn, kidx, nkept, pacc, ps, qe, ke, ve, nbr, degp, aoe);
  // K3b: combine splits -> aon (CP barrier beats device-scope fences)
  attn_reduce_kernel<<<dim3(N_NODES * HEADS * DH / 256), 256, 0, stream>>>(
      pacc, ps, aon);
  // K4: merged ue-GEMMs + gelu -> hb
  tail_kernel<<<dim3(N_EDGES / 8), 256, 0, stream>>>(
      aoe, wo_e, bo_e, aon, src, dst, wfu, bfu, w_c1, b_c1, hb);
  // K5: out = h @ w_c2 + b_c2
  gemm_out_kernel<<<dim3(N_EDGES / 8), 256, 0, stream>>>(hb, w_c2, b_c2,
                                                         (float*)d_out);
}